// Round 16
// baseline (845.851 us; speedup 1.0000x reference)
//
#include <hip/hip_runtime.h>

typedef unsigned short u16;
typedef unsigned int u32;
typedef __attribute__((ext_vector_type(8))) short short8;
typedef __attribute__((ext_vector_type(8))) _Float16 half8;
typedef __attribute__((ext_vector_type(4))) float f32x4;

#define NB 2
#define NT 2048
#define NC 2048
#define NHV 32
#define VALD 4096
#define NBT 4096
#define CL 64
#define NCH (NT / CL)

static __device__ __forceinline__ float bf2f(u16 u) {
  union { u32 u; float f; } x; x.u = ((u32)u) << 16; return x.f;
}
static __device__ __forceinline__ u16 f2bf(float f) {
  union { float f; u32 u; } x; x.f = f;
  u32 r = x.u + 0x7fffu + ((x.u >> 16) & 1u);
  return (u16)(r >> 16);
}
static __device__ __forceinline__ u16 f2h(float f) {
  union { _Float16 h; u16 u; } c; c.h = (_Float16)f; return c.u;
}
static __device__ __forceinline__ float h2f(u16 u) {
  union { u16 u; _Float16 h; } c; c.u = u; return (float)c.h;
}
static __device__ __forceinline__ float sigm(float x) { return 1.0f / (1.0f + __expf(-x)); }
static __device__ __forceinline__ int ldsoff(int row, int c8) {
  return row * 48 + ((c8 ^ ((row >> 2) & 3)) << 3);
}

// ---------------- sentinel ----------------
__global__ void k_sentinel(float* out) { out[0] = 1.0e6f; }

// ---------------- x -> bf16 hi/lo planes + fp16 plane (single read of x) ----------------
__global__ __launch_bounds__(256) void k_cvtx(const float* __restrict__ in, u16* __restrict__ hi,
                                              u16* __restrict__ lo, u16* __restrict__ h16, int n4) {
  int i = blockIdx.x * 256 + threadIdx.x;
  if (i >= n4) return;
  float4 v = ((const float4*)in)[i];
  ushort4 h, l, p;
  h.x = f2bf(v.x); l.x = f2bf(v.x - bf2f(h.x)); p.x = f2h(v.x);
  h.y = f2bf(v.y); l.y = f2bf(v.y - bf2f(h.y)); p.y = f2h(v.y);
  h.z = f2bf(v.z); l.z = f2bf(v.z - bf2f(h.z)); p.z = f2h(v.z);
  h.w = f2bf(v.w); l.w = f2bf(v.w - bf2f(h.w)); p.w = f2h(v.w);
  ((ushort4*)hi)[i] = h;
  ((ushort4*)lo)[i] = l;
  ((ushort4*)h16)[i] = p;
}

// ---------------- f32 -> fp16 plane ----------------
__global__ __launch_bounds__(256) void k_cvt16(const float* __restrict__ in, u16* __restrict__ out, int n4) {
  int i = blockIdx.x * 256 + threadIdx.x;
  if (i >= n4) return;
  float4 v = ((const float4*)in)[i];
  ushort4 o;
  o.x = f2h(v.x); o.y = f2h(v.y); o.z = f2h(v.z); o.w = f2h(v.w);
  ((ushort4*)out)[i] = o;
}

// ---------------- build padded W_ba hi/lo bf16 planes [128][2048] ----------------
__global__ __launch_bounds__(256) void k_wba(const float* __restrict__ Wb, const float* __restrict__ Wa,
                                             u16* __restrict__ hi, u16* __restrict__ lo) {
  int i = blockIdx.x * 256 + threadIdx.x;
  int r = i >> 11, c = i & 2047;
  float v = 0.f;
  if (r < 32) v = Wb[r * 2048 + c];
  else if (r < 64) v = Wa[(r - 32) * 2048 + c];
  u16 h = f2bf(v);
  hi[i] = h;
  lo[i] = f2bf(v - bf2f(h));
}

// ---------------- 3-pass bf16 GEMM (ba projection; recurrence-gate path) ----------------
__global__ __launch_bounds__(256) void k_gemm_bf3(const u16* __restrict__ Ahg, const u16* __restrict__ Alg,
                                                  const u16* __restrict__ Bhg, const u16* __restrict__ Blg,
                                                  float* __restrict__ C0, int M, int N, int K) {
  __shared__ __align__(16) u16 As_h[128 * 48];
  __shared__ __align__(16) u16 As_l[128 * 48];
  __shared__ __align__(16) u16 Bs_h[128 * 48];
  __shared__ __align__(16) u16 Bs_l[128 * 48];
  const int tid = threadIdx.x;
  const int lane = tid & 63, wave = tid >> 6;
  const int wr = wave >> 1, wc = wave & 1;
  const int l15 = lane & 15, l16 = lane >> 4;
  const int row0 = blockIdx.y * 128, col0 = blockIdx.x * 128;
  const int sr = tid >> 1, sk = (tid & 1) * 16;
  const int c0 = sk >> 3;
  const int w0 = ldsoff(sr, c0), w1 = ldsoff(sr, c0 + 1);
  f32x4 acc[4][4] = {};
  for (int k0 = 0; k0 < K; k0 += 32) {
    const size_t aoff = (size_t)(row0 + sr) * K + k0 + sk;
    const size_t boff = (size_t)(col0 + sr) * K + k0 + sk;
    *(short8*)&As_h[w0] = *(const short8*)&Ahg[aoff];
    *(short8*)&As_h[w1] = *(const short8*)&Ahg[aoff + 8];
    *(short8*)&As_l[w0] = *(const short8*)&Alg[aoff];
    *(short8*)&As_l[w1] = *(const short8*)&Alg[aoff + 8];
    *(short8*)&Bs_h[w0] = *(const short8*)&Bhg[boff];
    *(short8*)&Bs_h[w1] = *(const short8*)&Bhg[boff + 8];
    *(short8*)&Bs_l[w0] = *(const short8*)&Blg[boff];
    *(short8*)&Bs_l[w1] = *(const short8*)&Blg[boff + 8];
    __syncthreads();
    short8 ah[4], al[4], bh[4], bl[4];
#pragma unroll
    for (int mi = 0; mi < 4; ++mi) {
      int off = ldsoff(wr * 64 + mi * 16 + l15, l16);
      ah[mi] = *(short8*)&As_h[off];
      al[mi] = *(short8*)&As_l[off];
    }
#pragma unroll
    for (int ni = 0; ni < 4; ++ni) {
      int off = ldsoff(wc * 64 + ni * 16 + l15, l16);
      bh[ni] = *(short8*)&Bs_h[off];
      bl[ni] = *(short8*)&Bs_l[off];
    }
#pragma unroll
    for (int mi = 0; mi < 4; ++mi)
#pragma unroll
      for (int ni = 0; ni < 4; ++ni) {
        acc[mi][ni] = __builtin_amdgcn_mfma_f32_16x16x32_bf16(ah[mi], bh[ni], acc[mi][ni], 0, 0, 0);
        acc[mi][ni] = __builtin_amdgcn_mfma_f32_16x16x32_bf16(al[mi], bh[ni], acc[mi][ni], 0, 0, 0);
        acc[mi][ni] = __builtin_amdgcn_mfma_f32_16x16x32_bf16(ah[mi], bl[ni], acc[mi][ni], 0, 0, 0);
      }
    __syncthreads();
  }
#pragma unroll
  for (int mi = 0; mi < 4; ++mi)
#pragma unroll
    for (int ni = 0; ni < 4; ++ni) {
      int rr = row0 + wr * 64 + mi * 16 + l16 * 4;
      int cc = col0 + wc * 64 + ni * 16 + l15;
#pragma unroll
      for (int i = 0; i < 4; ++i)
        C0[(size_t)(rr + i) * N + cc] = acc[mi][ni][i];
    }
}

// ---------------- single-pass fp16 GEMM, 256x256 tile, 8 waves ----------------
// C = A[M][K] * B[N][K]^T. Wave grid 2(M)x4(N); per-wave out 128x64 (mapping verified in r10).
// MODE 0: f32 out. MODE 1: fp16 out. MODE 2: z epilogue -> fp16 out.
// 1D grid with bijective XCD swizzle (nblocks % 8 == 0).
template <int MODE>
__global__ __launch_bounds__(512) void k_gemm16(const u16* __restrict__ Ag, const u16* __restrict__ Bg,
                                                void* __restrict__ C0, int M, int N, int K,
                                                const float* __restrict__ e0, const float* __restrict__ e1,
                                                const float* __restrict__ e2) {
  __shared__ __align__(16) u16 As[256 * 40];
  __shared__ __align__(16) u16 Bs[256 * 40];
  const int tid = threadIdx.x;
  const int lane = tid & 63, wv = tid >> 6;
  const int l15 = lane & 15, l16 = lane >> 4;
  const int nbx = N >> 8;
  const int nwg = gridDim.x;
  const int q = nwg >> 3;
  const int bid = blockIdx.x;
  const int swz = (bid & 7) * q + (bid >> 3);
  const int bx = swz % nbx, by = swz / nbx;
  const int row0 = by * 256, col0 = bx * 256;
  const int wr = wv >> 2, wc = wv & 3;
  const int sr = tid >> 1, sk = (tid & 1) * 16;
  f32x4 acc[8][4] = {};
  for (int k0 = 0; k0 < K; k0 += 32) {
    const size_t aoff = (size_t)(row0 + sr) * K + k0 + sk;
    const size_t boff = (size_t)(col0 + sr) * K + k0 + sk;
    *(short8*)&As[sr * 40 + sk] = *(const short8*)&Ag[aoff];
    *(short8*)&As[sr * 40 + sk + 8] = *(const short8*)&Ag[aoff + 8];
    *(short8*)&Bs[sr * 40 + sk] = *(const short8*)&Bg[boff];
    *(short8*)&Bs[sr * 40 + sk + 8] = *(const short8*)&Bg[boff + 8];
    __syncthreads();
    half8 a[8], b[4];
#pragma unroll
    for (int mi = 0; mi < 8; ++mi) a[mi] = *(half8*)&As[(wr * 128 + mi * 16 + l15) * 40 + l16 * 8];
#pragma unroll
    for (int ni = 0; ni < 4; ++ni) b[ni] = *(half8*)&Bs[(wc * 64 + ni * 16 + l15) * 40 + l16 * 8];
#pragma unroll
    for (int mi = 0; mi < 8; ++mi)
#pragma unroll
      for (int ni = 0; ni < 4; ++ni)
        acc[mi][ni] = __builtin_amdgcn_mfma_f32_16x16x32_f16(a[mi], b[ni], acc[mi][ni], 0, 0, 0);
    __syncthreads();
  }
#pragma unroll
  for (int mi = 0; mi < 8; ++mi) {
#pragma unroll
    for (int ni = 0; ni < 4; ++ni) {
      int rr = row0 + wr * 128 + mi * 16 + l16 * 4;
      int cc = col0 + wc * 64 + ni * 16 + l15;
#pragma unroll
      for (int i = 0; i < 4; ++i) {
        float v = acc[mi][ni][i];
        size_t idx = (size_t)(rr + i) * N + cc;
        if constexpr (MODE == 0) {
          ((float*)C0)[idx] = v;
        } else if constexpr (MODE == 1) {
          ((u16*)C0)[idx] = f2h(v);
        } else {
          float zs = v * sigm(v);
          float o = e0[idx] * e1[(size_t)(rr + i) * 32 + (cc >> 7)] * e2[cc & 127] * zs;
          ((u16*)C0)[idx] = f2h(o);
        }
      }
    }
  }
}

// ---------------- beta / g from ba [BT,128] f32, TRANSPOSED out [32][4096] ----------------
__global__ __launch_bounds__(256) void k_bg(const float* __restrict__ ba, const float* __restrict__ dt_bias,
                                            const float* __restrict__ A_log, float* __restrict__ beta_t,
                                            float* __restrict__ g_t) {
  int i = blockIdx.x * 256 + threadIdx.x;
  int bt = i >> 5, h = i & 31;
  float bv = ba[(size_t)bt * 128 + h];
  float av = ba[(size_t)bt * 128 + 32 + h];
  beta_t[h * 4096 + bt] = sigm(bv);
  float xx = av + dt_bias[h];
  float sp = (xx > 20.f) ? xx : log1pf(__expf(xx));
  g_t[h * 4096 + bt] = -__expf(A_log[h]) * sp;
}

// ---------------- conv+SiLU+L2norm for q,k: fp16 in [4096][4096] -> fp16 out ----------------
__global__ __launch_bounds__(256) void k_convqk(const u16* __restrict__ qkraw, const float* __restrict__ cw,
                                                u16* __restrict__ qkn) {
  __shared__ float sval[4096];
  __shared__ float snrm[32];
  const int tid = threadIdx.x;
  const int bt = blockIdx.x;
  const int b = bt >> 11, t = bt & 2047;
  for (int i = 0; i < 16; ++i) {
    int c = i * 256 + tid;
    float acc = 0.f;
#pragma unroll
    for (int j = 0; j < 4; ++j) {
      int ts = t - 3 + j;
      if (ts >= 0) acc += cw[c * 4 + j] * h2f(qkraw[(size_t)(b * 2048 + ts) * 4096 + c]);
    }
    sval[c] = acc * sigm(acc);
  }
  __syncthreads();
  {
    int gidx = tid >> 3, s = tid & 7;
    float ss = 0.f;
#pragma unroll
    for (int i2 = 0; i2 < 16; ++i2) { float v = sval[gidx * 128 + s * 16 + i2]; ss += v * v; }
    ss += __shfl_xor(ss, 1); ss += __shfl_xor(ss, 2); ss += __shfl_xor(ss, 4);
    if (s == 0) snrm[gidx] = 1.0f / fmaxf(sqrtf(ss), 1e-12f);
  }
  __syncthreads();
  for (int i = 0; i < 16; ++i) {
    int c = i * 256 + tid;
    qkn[(size_t)bt * 4096 + c] = f2h(sval[c] * snrm[c >> 7]);
  }
}

// ---------------- chunked gated-linear-attention scan, single-fp16 MFMA ----------------
// grid 256 = dq(4) x h(32) x b(2); block 512 (8 waves); ~71 KB LDS -> 2 blocks/CU.
__global__ __launch_bounds__(512, 4) void k_scanc(const u16* __restrict__ qk16, const u16* __restrict__ v16,
                                                  const float* __restrict__ cw,
                                                  const float* __restrict__ beta_t, const float* __restrict__ g_t,
                                                  float* __restrict__ outr) {
  __shared__ __align__(16) u16 Qs[64][136], Ks[64][136];
  __shared__ __align__(16) u16 Vs[32][72];
  __shared__ __align__(16) u16 SIs[64][72];
  __shared__ __align__(16) u16 SH[2][32][132];
  __shared__ u16 rv16[67][36];
  __shared__ float garr[64], barr[64], warr[64], earr[64];
  __shared__ float sdt;

  const int tid = threadIdx.x;
  const int lane = tid & 63, wv = tid >> 6;
  const int l15 = lane & 15, l16 = lane >> 4;
  const int dq = blockIdx.x & 3, h = (blockIdx.x >> 2) & 31, b = blockIdx.x >> 7;
  const int bT = b * 2048;
  const int hk = h >> 1;
  const int dvl = tid & 31;
  const int vch = h * 128 + dq * 32;
  const float4 cwv = *(const float4*)&cw[(4096 + vch + dvl) * 4];
  const int mblk = wv & 3, nh = wv >> 2;
  const int m0 = mblk * 16;
  const int sr = tid >> 3, d0 = (tid & 7) * 16;
  const int r0v = tid >> 5;

  for (int i = tid; i < 2 * 32 * 132; i += 512) ((u16*)SH)[i] = 0;
  f32x4 st[2] = {};

  short8 pq[2], pk[2];
  u16 pv[5];
  auto LOADQK = [&](int t0) {
    const size_t base = (size_t)(bT + t0 + sr) * 4096 + hk * 128 + d0;
    pq[0] = *(const short8*)&qk16[base];        pq[1] = *(const short8*)&qk16[base + 8];
    pk[0] = *(const short8*)&qk16[base + 2048]; pk[1] = *(const short8*)&qk16[base + 2056];
  };
  auto LOADV = [&](int t0) {
#pragma unroll
    for (int i = 0; i < 5; ++i) {
      int r = r0v + i * 16;
      int tr = t0 - 3 + r;
      pv[i] = (r < 67 && tr >= 0) ? v16[(size_t)(bT + tr) * 4096 + vch + dvl] : (u16)0;
    }
  };

  LOADQK(0);
  LOADV(0);

  for (int ch = 0; ch < NCH; ++ch) {
    const int t0 = ch * CL;
    const int p = ch & 1;
    *(short8*)&Qs[sr][d0] = pq[0]; *(short8*)&Qs[sr][d0 + 8] = pq[1];
    *(short8*)&Ks[sr][d0] = pk[0]; *(short8*)&Ks[sr][d0 + 8] = pk[1];
#pragma unroll
    for (int i = 0; i < 5; ++i) {
      int r = r0v + i * 16;
      if (r < 67) rv16[r][dvl] = pv[i];
    }
    if (wv == 0) {
      float gv = g_t[h * 4096 + bT + t0 + lane];
      float bv = beta_t[h * 4096 + bT + t0 + lane];
      float cum = gv;
#pragma unroll
      for (int off = 1; off < 64; off <<= 1) {
        float o = __shfl_up(cum, off);
        if (lane >= off) cum += o;
      }
      float tot = __shfl(cum, 63);
      garr[lane] = cum;
      earr[lane] = __expf(cum);
      warr[lane] = __expf(tot - cum) * bv;
      barr[lane] = bv;
      if (lane == 0) sdt = __expf(tot);
    }
    __syncthreads();  // B1
    if (ch + 1 < NCH) {
      LOADQK(t0 + CL);
      LOADV(t0 + CL);
    }
    // ---- v conv + silu -> fp16 transposed [dv][s]
    {
      int tl = tid >> 5;
#pragma unroll
      for (int rr = 0; rr < 4; ++rr) {
        int t = rr * 16 + tl;
        float a = cwv.x * h2f(rv16[t][dvl]) + cwv.y * h2f(rv16[t + 1][dvl]) +
                  cwv.z * h2f(rv16[t + 2][dvl]) + cwv.w * h2f(rv16[t + 3][dvl]);
        a = a * sigm(a);
        Vs[dvl][t] = f2h(a);
      }
    }
    // ---- A = Q K^T; this wave: rows m0..m0+15, col blocks nh*2, nh*2+1
    half8 a[4];
#pragma unroll
    for (int kk = 0; kk < 4; ++kk) a[kk] = *(half8*)&Qs[m0 + l15][l16 * 8 + kk * 32];
#pragma unroll
    for (int j = 0; j < 2; ++j) {
      int n = nh * 2 + j;
      f32x4 a4 = {};
#pragma unroll
      for (int kk = 0; kk < 4; ++kk) {
        half8 b8 = *(half8*)&Ks[n * 16 + l15][l16 * 8 + kk * 32];
        a4 = __builtin_amdgcn_mfma_f32_16x16x32_f16(a[kk], b8, a4, 0, 0, 0);
      }
      int col = n * 16 + l15;
      float gc = garr[col], bc = barr[col];
#pragma unroll
      for (int i = 0; i < 4; ++i) {
        int row = m0 + l16 * 4 + i;
        float cval = (col <= row) ? __expf(garr[row] - gc) * bc * a4[i] : 0.f;
        SIs[row][col] = f2h(cval);
      }
    }
    __syncthreads();  // B2
    // ---- out_inter = Q @ St_prev, scaled by e^{Gc[t]}
    f32x4 ao = {};
#pragma unroll
    for (int kk = 0; kk < 4; ++kk) {
      half8 s8 = *(half8*)&SH[p][nh * 16 + l15][l16 * 8 + kk * 32];
      ao = __builtin_amdgcn_mfma_f32_16x16x32_f16(a[kk], s8, ao, 0, 0, 0);
    }
#pragma unroll
    for (int i = 0; i < 4; ++i) ao[i] *= earr[m0 + l16 * 4 + i];
    // ---- out += SI @ V
#pragma unroll
    for (int kk = 0; kk < 2; ++kk) {
      half8 asi = *(half8*)&SIs[m0 + l15][l16 * 8 + kk * 32];
      half8 bv8 = *(half8*)&Vs[nh * 16 + l15][l16 * 8 + kk * 32];
      ao = __builtin_amdgcn_mfma_f32_16x16x32_f16(asi, bv8, ao, 0, 0, 0);
    }
#pragma unroll
    for (int i = 0; i < 4; ++i)
      outr[(size_t)(bT + t0 + m0 + l16 * 4 + i) * 4096 + vch + nh * 16 + l15] = ao[i];
    // ---- state update: St = sdt*St + V^T (K.w); this wave: dk band wv*16
#pragma unroll
    for (int m = 0; m < 2; ++m)
#pragma unroll
      for (int i = 0; i < 4; ++i) st[m][i] *= sdt;
#pragma unroll
    for (int kk = 0; kk < 2; ++kk) {
      half8 bw;
      {
        int dk = wv * 16 + l15;
#pragma unroll
        for (int e = 0; e < 8; ++e) {
          int s = l16 * 8 + e + kk * 32;
          bw[e] = (_Float16)(h2f(Ks[s][dk]) * warr[s]);
        }
      }
#pragma unroll
      for (int m = 0; m < 2; ++m) {
        half8 av = *(half8*)&Vs[m * 16 + l15][l16 * 8 + kk * 32];
        st[m] = __builtin_amdgcn_mfma_f32_16x16x32_f16(av, bw, st[m], 0, 0, 0);
      }
    }
#pragma unroll
    for (int m = 0; m < 2; ++m)
#pragma unroll
      for (int i = 0; i < 4; ++i)
        SH[p ^ 1][m * 16 + l16 * 4 + i][wv * 16 + l15] = f2h(st[m][i]);
    __syncthreads();  // B4
  }
}

// ---------------- per-(bt,head) RMS scale from f32 outr ----------------
__global__ __launch_bounds__(256) void k_rms(const float* __restrict__ outr, float* __restrict__ rms) {
  int pair = blockIdx.x * 4 + (threadIdx.x >> 6);
  int lane = threadIdx.x & 63;
  float2 v = *(const float2*)&outr[(size_t)pair * 128 + lane * 2];
  float ss = v.x * v.x + v.y * v.y;
#pragma unroll
  for (int m = 1; m < 64; m <<= 1) ss += __shfl_xor(ss, m);
  if (lane == 0) rms[pair] = rsqrtf(ss * (1.0f / 128.0f) + 1e-6f);
}

extern "C" void kernel_launch(void* const* d_in, const int* in_sizes, int n_in,
                              void* d_out, int out_size, void* d_ws, size_t ws_size,
                              hipStream_t stream) {
  const float* x = (const float*)d_in[0];
  // d_in[1] = positions (int64) — unused by the math
  const float* W_qkv = (const float*)d_in[2];
  const float* W_z = (const float*)d_in[3];
  const float* W_b = (const float*)d_in[4];
  const float* W_a = (const float*)d_in[5];
  const float* conv_w = (const float*)d_in[6];
  const float* dt_bias = (const float*)d_in[7];
  const float* A_log = (const float*)d_in[8];
  const float* norm_w = (const float*)d_in[9];
  const float* W_out = (const float*)d_in[10];
  float* out = (float*)d_out;

  const size_t MB = 1ull << 20;
  const size_t need = 192 * MB + 3 * (size_t)NBT * 32 * 4;  // == proven bound
  if (ws_size < need) {
    k_sentinel<<<1, 1, 0, stream>>>(out);
    return;
  }
  char* ws = (char*)d_ws;
  // Region A [0,64MB): xh | xl | xh16 | spare. Later: outr f32 (full). Later: wout16 [0,16).
  u16* xh = (u16*)ws;
  u16* xl = (u16*)(ws + 16 * MB);
  u16* xh16 = (u16*)(ws + 32 * MB);
  float* outr = (float*)ws;
  u16* wout16 = (u16*)ws;
  // Region B [64,128MB): early wba+babuf [64,67); qkA16 [96,128); qkB16 [64,96); om16 [96,128).
  u16* wbah = (u16*)(ws + 64 * MB);
  u16* wbal = (u16*)(ws + 64 * MB + 512 * 1024);
  float* babuf = (float*)(ws + 65 * MB);
  u16* qkB16 = (u16*)(ws + 64 * MB);
  u16* qkA16 = (u16*)(ws + 96 * MB);
  u16* om16 = (u16*)(ws + 96 * MB);
  // Region C [128,192MB): wsh16 full [128,160); v16 [160,192). Later xh16b [128,144), wz16 [144,160).
  u16* wsh16 = (u16*)(ws + 128 * MB);
  u16* v16 = (u16*)(ws + 160 * MB);
  u16* xh16b = (u16*)(ws + 128 * MB);
  u16* wz16 = (u16*)(ws + 144 * MB);
  float* beta_t = (float*)(ws + 192 * MB);
  float* g_t = beta_t + (size_t)NBT * 32;
  float* rmsb = g_t + (size_t)NBT * 32;

  const int N4X = NBT * NC / 4;
  // --- conversions + ba path ---
  k_cvtx<<<N4X / 256, 256, 0, stream>>>(x, xh, xl, xh16, N4X);
  k_cvt16<<<2 * N4X / 256, 256, 0, stream>>>(W_qkv, wsh16, 2 * N4X);  // full 8192 rows
  k_wba<<<128 * NC / 256, 256, 0, stream>>>(W_b, W_a, wbah, wbal);
  k_gemm_bf3<<<dim3(1, NBT / 128), 256, 0, stream>>>(xh, xl, wbah, wbal, babuf, NBT, 128, NC);
  k_bg<<<NBT * 32 / 256, 256, 0, stream>>>(babuf, dt_bias, A_log, beta_t, g_t);

  // --- qk projection (fp16, 256^2 tile) -> conv+norm -> qkB16 ---
  k_gemm16<1><<<(NBT / 256) * (4096 / 256), 512, 0, stream>>>(xh16, wsh16, qkA16, NBT, 4096, NC,
                                                              nullptr, nullptr, nullptr);
  k_convqk<<<NBT, 256, 0, stream>>>(qkA16, conv_w, qkB16);

  // --- v projection (fp16, 256^2 tile) ---
  k_gemm16<1><<<(NBT / 256) * (4096 / 256), 512, 0, stream>>>(xh16, wsh16 + (size_t)4096 * NC, v16,
                                                              NBT, 4096, NC, nullptr, nullptr, nullptr);

  // --- chunked scan -> outr (overlays x planes, dead) ---
  k_scanc<<<256, 512, 0, stream>>>(qkB16, v16, conv_w, beta_t, g_t, outr);
  k_rms<<<NBT * NHV / 4, 256, 0, stream>>>(outr, rmsb);

  // --- z projection (fp16, 256^2 tile) with fused gate epilogue -> om16 (qkA16 dead) ---
  k_cvt16<<<N4X / 256, 256, 0, stream>>>(x, xh16b, N4X);
  k_cvt16<<<N4X / 256, 256, 0, stream>>>(W_z, wz16, N4X);
  k_gemm16<2><<<(NBT / 256) * (VALD / 256), 512, 0, stream>>>(xh16b, wz16, om16, NBT, VALD, NC,
                                                              outr, rmsb, norm_w);

  // --- output projection (fp16, 256^2 tile) -> f32 out (outr dead -> wout16 overlay) ---
  k_cvt16<<<N4X / 256, 256, 0, stream>>>(W_out, wout16, N4X);
  k_gemm16<0><<<(NBT / 256) * (NC / 256), 512, 0, stream>>>(om16, wout16, out, NBT, NC, VALD,
                                                            nullptr, nullptr, nullptr);
}

// Round 17
// 751.309 us; speedup vs baseline: 1.1258x; 1.1258x over previous
//
#include <hip/hip_runtime.h>

typedef unsigned short u16;
typedef unsigned int u32;
typedef __attribute__((ext_vector_type(8))) short short8;
typedef __attribute__((ext_vector_type(8))) _Float16 half8;
typedef __attribute__((ext_vector_type(4))) float f32x4;

#define NB 2
#define NT 2048
#define NC 2048
#define NHV 32
#define VALD 4096
#define NBT 4096
#define CL 64
#define NCH (NT / CL)

static __device__ __forceinline__ float bf2f(u16 u) {
  union { u32 u; float f; } x; x.u = ((u32)u) << 16; return x.f;
}
static __device__ __forceinline__ u16 f2bf(float f) {
  union { float f; u32 u; } x; x.f = f;
  u32 r = x.u + 0x7fffu + ((x.u >> 16) & 1u);
  return (u16)(r >> 16);
}
static __device__ __forceinline__ u16 f2h(float f) {
  union { _Float16 h; u16 u; } c; c.h = (_Float16)f; return c.u;
}
static __device__ __forceinline__ float h2f(u16 u) {
  union { u16 u; _Float16 h; } c; c.u = u; return (float)c.h;
}
static __device__ __forceinline__ float sigm(float x) { return 1.0f / (1.0f + __expf(-x)); }
static __device__ __forceinline__ int ldsoff(int row, int c8) {
  return row * 48 + ((c8 ^ ((row >> 2) & 3)) << 3);
}

// ---------------- sentinel ----------------
__global__ void k_sentinel(float* out) { out[0] = 1.0e6f; }

// ---------------- x -> bf16 hi/lo planes + fp16 plane (single read of x) ----------------
__global__ __launch_bounds__(256) void k_cvtx(const float* __restrict__ in, u16* __restrict__ hi,
                                              u16* __restrict__ lo, u16* __restrict__ h16, int n4) {
  int i = blockIdx.x * 256 + threadIdx.x;
  if (i >= n4) return;
  float4 v = ((const float4*)in)[i];
  ushort4 h, l, p;
  h.x = f2bf(v.x); l.x = f2bf(v.x - bf2f(h.x)); p.x = f2h(v.x);
  h.y = f2bf(v.y); l.y = f2bf(v.y - bf2f(h.y)); p.y = f2h(v.y);
  h.z = f2bf(v.z); l.z = f2bf(v.z - bf2f(h.z)); p.z = f2h(v.z);
  h.w = f2bf(v.w); l.w = f2bf(v.w - bf2f(h.w)); p.w = f2h(v.w);
  ((ushort4*)hi)[i] = h;
  ((ushort4*)lo)[i] = l;
  ((ushort4*)h16)[i] = p;
}

// ---------------- f32 -> fp16 plane ----------------
__global__ __launch_bounds__(256) void k_cvt16(const float* __restrict__ in, u16* __restrict__ out, int n4) {
  int i = blockIdx.x * 256 + threadIdx.x;
  if (i >= n4) return;
  float4 v = ((const float4*)in)[i];
  ushort4 o;
  o.x = f2h(v.x); o.y = f2h(v.y); o.z = f2h(v.z); o.w = f2h(v.w);
  ((ushort4*)out)[i] = o;
}

// ---------------- build padded W_ba hi/lo bf16 planes [128][2048] ----------------
__global__ __launch_bounds__(256) void k_wba(const float* __restrict__ Wb, const float* __restrict__ Wa,
                                             u16* __restrict__ hi, u16* __restrict__ lo) {
  int i = blockIdx.x * 256 + threadIdx.x;
  int r = i >> 11, c = i & 2047;
  float v = 0.f;
  if (r < 32) v = Wb[r * 2048 + c];
  else if (r < 64) v = Wa[(r - 32) * 2048 + c];
  u16 h = f2bf(v);
  hi[i] = h;
  lo[i] = f2bf(v - bf2f(h));
}

// ---------------- 3-pass bf16 GEMM (ba projection; recurrence-gate path) ----------------
__global__ __launch_bounds__(256) void k_gemm_bf3(const u16* __restrict__ Ahg, const u16* __restrict__ Alg,
                                                  const u16* __restrict__ Bhg, const u16* __restrict__ Blg,
                                                  float* __restrict__ C0, int M, int N, int K) {
  __shared__ __align__(16) u16 As_h[128 * 48];
  __shared__ __align__(16) u16 As_l[128 * 48];
  __shared__ __align__(16) u16 Bs_h[128 * 48];
  __shared__ __align__(16) u16 Bs_l[128 * 48];
  const int tid = threadIdx.x;
  const int lane = tid & 63, wave = tid >> 6;
  const int wr = wave >> 1, wc = wave & 1;
  const int l15 = lane & 15, l16 = lane >> 4;
  const int row0 = blockIdx.y * 128, col0 = blockIdx.x * 128;
  const int sr = tid >> 1, sk = (tid & 1) * 16;
  const int c0 = sk >> 3;
  const int w0 = ldsoff(sr, c0), w1 = ldsoff(sr, c0 + 1);
  f32x4 acc[4][4] = {};
  for (int k0 = 0; k0 < K; k0 += 32) {
    const size_t aoff = (size_t)(row0 + sr) * K + k0 + sk;
    const size_t boff = (size_t)(col0 + sr) * K + k0 + sk;
    *(short8*)&As_h[w0] = *(const short8*)&Ahg[aoff];
    *(short8*)&As_h[w1] = *(const short8*)&Ahg[aoff + 8];
    *(short8*)&As_l[w0] = *(const short8*)&Alg[aoff];
    *(short8*)&As_l[w1] = *(const short8*)&Alg[aoff + 8];
    *(short8*)&Bs_h[w0] = *(const short8*)&Bhg[boff];
    *(short8*)&Bs_h[w1] = *(const short8*)&Bhg[boff + 8];
    *(short8*)&Bs_l[w0] = *(const short8*)&Blg[boff];
    *(short8*)&Bs_l[w1] = *(const short8*)&Blg[boff + 8];
    __syncthreads();
    short8 ah[4], al[4], bh[4], bl[4];
#pragma unroll
    for (int mi = 0; mi < 4; ++mi) {
      int off = ldsoff(wr * 64 + mi * 16 + l15, l16);
      ah[mi] = *(short8*)&As_h[off];
      al[mi] = *(short8*)&As_l[off];
    }
#pragma unroll
    for (int ni = 0; ni < 4; ++ni) {
      int off = ldsoff(wc * 64 + ni * 16 + l15, l16);
      bh[ni] = *(short8*)&Bs_h[off];
      bl[ni] = *(short8*)&Bs_l[off];
    }
#pragma unroll
    for (int mi = 0; mi < 4; ++mi)
#pragma unroll
      for (int ni = 0; ni < 4; ++ni) {
        acc[mi][ni] = __builtin_amdgcn_mfma_f32_16x16x32_bf16(ah[mi], bh[ni], acc[mi][ni], 0, 0, 0);
        acc[mi][ni] = __builtin_amdgcn_mfma_f32_16x16x32_bf16(al[mi], bh[ni], acc[mi][ni], 0, 0, 0);
        acc[mi][ni] = __builtin_amdgcn_mfma_f32_16x16x32_bf16(ah[mi], bl[ni], acc[mi][ni], 0, 0, 0);
      }
    __syncthreads();
  }
#pragma unroll
  for (int mi = 0; mi < 4; ++mi)
#pragma unroll
    for (int ni = 0; ni < 4; ++ni) {
      int rr = row0 + wr * 64 + mi * 16 + l16 * 4;
      int cc = col0 + wc * 64 + ni * 16 + l15;
#pragma unroll
      for (int i = 0; i < 4; ++i)
        C0[(size_t)(rr + i) * N + cc] = acc[mi][ni][i];
    }
}

// ---------------- single-pass fp16 GEMM, 128x128 tile, BK=64 ----------------
// C = A[M][K] * B[N][K]^T. 256 threads, 4 waves (2Mx2N), per-wave 64x64.
// MODE 0: f32 out. MODE 1: fp16 out. MODE 2: z epilogue -> fp16 out.
template <int MODE>
__global__ __launch_bounds__(256) void k_gemm16(const u16* __restrict__ Ag, const u16* __restrict__ Bg,
                                                void* __restrict__ C0, int M, int N, int K,
                                                const float* __restrict__ e0, const float* __restrict__ e1,
                                                const float* __restrict__ e2) {
  __shared__ __align__(16) u16 As[128 * 72];
  __shared__ __align__(16) u16 Bs[128 * 72];
  const int tid = threadIdx.x;
  const int lane = tid & 63, wave = tid >> 6;
  const int wr = wave >> 1, wc = wave & 1;
  const int l15 = lane & 15, l16 = lane >> 4;
  const int row0 = blockIdx.y * 128, col0 = blockIdx.x * 128;
  const int sr = tid >> 1, sk = (tid & 1) * 32;
  f32x4 acc[4][4] = {};
  for (int k0 = 0; k0 < K; k0 += 64) {
    const size_t aoff = (size_t)(row0 + sr) * K + k0 + sk;
    const size_t boff = (size_t)(col0 + sr) * K + k0 + sk;
#pragma unroll
    for (int c = 0; c < 4; ++c) {
      *(short8*)&As[sr * 72 + sk + c * 8] = *(const short8*)&Ag[aoff + c * 8];
      *(short8*)&Bs[sr * 72 + sk + c * 8] = *(const short8*)&Bg[boff + c * 8];
    }
    __syncthreads();
#pragma unroll
    for (int kk = 0; kk < 2; ++kk) {
      half8 a[4], b[4];
#pragma unroll
      for (int mi = 0; mi < 4; ++mi)
        a[mi] = *(half8*)&As[(wr * 64 + mi * 16 + l15) * 72 + kk * 32 + l16 * 8];
#pragma unroll
      for (int ni = 0; ni < 4; ++ni)
        b[ni] = *(half8*)&Bs[(wc * 64 + ni * 16 + l15) * 72 + kk * 32 + l16 * 8];
#pragma unroll
      for (int mi = 0; mi < 4; ++mi)
#pragma unroll
        for (int ni = 0; ni < 4; ++ni)
          acc[mi][ni] = __builtin_amdgcn_mfma_f32_16x16x32_f16(a[mi], b[ni], acc[mi][ni], 0, 0, 0);
    }
    __syncthreads();
  }
#pragma unroll
  for (int mi = 0; mi < 4; ++mi) {
#pragma unroll
    for (int ni = 0; ni < 4; ++ni) {
      int rr = row0 + wr * 64 + mi * 16 + l16 * 4;
      int cc = col0 + wc * 64 + ni * 16 + l15;
#pragma unroll
      for (int i = 0; i < 4; ++i) {
        float v = acc[mi][ni][i];
        size_t idx = (size_t)(rr + i) * N + cc;
        if constexpr (MODE == 0) {
          ((float*)C0)[idx] = v;
        } else if constexpr (MODE == 1) {
          ((u16*)C0)[idx] = f2h(v);
        } else {
          float zs = v * sigm(v);
          float o = e0[idx] * e1[(size_t)(rr + i) * 32 + (cc >> 7)] * e2[cc & 127] * zs;
          ((u16*)C0)[idx] = f2h(o);
        }
      }
    }
  }
}

// ---------------- beta / g from ba [BT,128] f32, TRANSPOSED out [32][4096] ----------------
__global__ __launch_bounds__(256) void k_bg(const float* __restrict__ ba, const float* __restrict__ dt_bias,
                                            const float* __restrict__ A_log, float* __restrict__ beta_t,
                                            float* __restrict__ g_t) {
  int i = blockIdx.x * 256 + threadIdx.x;
  int bt = i >> 5, h = i & 31;
  float bv = ba[(size_t)bt * 128 + h];
  float av = ba[(size_t)bt * 128 + 32 + h];
  beta_t[h * 4096 + bt] = sigm(bv);
  float xx = av + dt_bias[h];
  float sp = (xx > 20.f) ? xx : log1pf(__expf(xx));
  g_t[h * 4096 + bt] = -__expf(A_log[h]) * sp;
}

// ---------------- conv+SiLU+L2norm for q,k: fp16 in [4096][4096] -> fp16 out ----------------
__global__ __launch_bounds__(256) void k_convqk(const u16* __restrict__ qkraw, const float* __restrict__ cw,
                                                u16* __restrict__ qkn) {
  __shared__ float sval[4096];
  __shared__ float snrm[32];
  const int tid = threadIdx.x;
  const int bt = blockIdx.x;
  const int b = bt >> 11, t = bt & 2047;
  for (int i = 0; i < 16; ++i) {
    int c = i * 256 + tid;
    float acc = 0.f;
#pragma unroll
    for (int j = 0; j < 4; ++j) {
      int ts = t - 3 + j;
      if (ts >= 0) acc += cw[c * 4 + j] * h2f(qkraw[(size_t)(b * 2048 + ts) * 4096 + c]);
    }
    sval[c] = acc * sigm(acc);
  }
  __syncthreads();
  {
    int gidx = tid >> 3, s = tid & 7;
    float ss = 0.f;
#pragma unroll
    for (int i2 = 0; i2 < 16; ++i2) { float v = sval[gidx * 128 + s * 16 + i2]; ss += v * v; }
    ss += __shfl_xor(ss, 1); ss += __shfl_xor(ss, 2); ss += __shfl_xor(ss, 4);
    if (s == 0) snrm[gidx] = 1.0f / fmaxf(sqrtf(ss), 1e-12f);
  }
  __syncthreads();
  for (int i = 0; i < 16; ++i) {
    int c = i * 256 + tid;
    qkn[(size_t)bt * 4096 + c] = f2h(sval[c] * snrm[c >> 7]);
  }
}

// ---------------- chunked gated-linear-attention scan, single-fp16 MFMA ----------------
// grid 256 = dq(4) x h(32) x b(2); block 512 (8 waves); ~71 KB LDS -> 2 blocks/CU.
__global__ __launch_bounds__(512, 4) void k_scanc(const u16* __restrict__ qk16, const u16* __restrict__ v16,
                                                  const float* __restrict__ cw,
                                                  const float* __restrict__ beta_t, const float* __restrict__ g_t,
                                                  float* __restrict__ outr) {
  __shared__ __align__(16) u16 Qs[64][136], Ks[64][136];
  __shared__ __align__(16) u16 Vs[32][72];
  __shared__ __align__(16) u16 SIs[64][72];
  __shared__ __align__(16) u16 SH[2][32][132];
  __shared__ u16 rv16[67][36];
  __shared__ float garr[64], barr[64], warr[64], earr[64];
  __shared__ float sdt;

  const int tid = threadIdx.x;
  const int lane = tid & 63, wv = tid >> 6;
  const int l15 = lane & 15, l16 = lane >> 4;
  const int dq = blockIdx.x & 3, h = (blockIdx.x >> 2) & 31, b = blockIdx.x >> 7;
  const int bT = b * 2048;
  const int hk = h >> 1;
  const int dvl = tid & 31;
  const int vch = h * 128 + dq * 32;
  const float4 cwv = *(const float4*)&cw[(4096 + vch + dvl) * 4];
  const int mblk = wv & 3, nh = wv >> 2;
  const int m0 = mblk * 16;
  const int sr = tid >> 3, d0 = (tid & 7) * 16;
  const int r0v = tid >> 5;

  for (int i = tid; i < 2 * 32 * 132; i += 512) ((u16*)SH)[i] = 0;
  f32x4 st[2] = {};

  short8 pq[2], pk[2];
  u16 pv[5];
  auto LOADQK = [&](int t0) {
    const size_t base = (size_t)(bT + t0 + sr) * 4096 + hk * 128 + d0;
    pq[0] = *(const short8*)&qk16[base];        pq[1] = *(const short8*)&qk16[base + 8];
    pk[0] = *(const short8*)&qk16[base + 2048]; pk[1] = *(const short8*)&qk16[base + 2056];
  };
  auto LOADV = [&](int t0) {
#pragma unroll
    for (int i = 0; i < 5; ++i) {
      int r = r0v + i * 16;
      int tr = t0 - 3 + r;
      pv[i] = (r < 67 && tr >= 0) ? v16[(size_t)(bT + tr) * 4096 + vch + dvl] : (u16)0;
    }
  };

  LOADQK(0);
  LOADV(0);

  for (int ch = 0; ch < NCH; ++ch) {
    const int t0 = ch * CL;
    const int p = ch & 1;
    *(short8*)&Qs[sr][d0] = pq[0]; *(short8*)&Qs[sr][d0 + 8] = pq[1];
    *(short8*)&Ks[sr][d0] = pk[0]; *(short8*)&Ks[sr][d0 + 8] = pk[1];
#pragma unroll
    for (int i = 0; i < 5; ++i) {
      int r = r0v + i * 16;
      if (r < 67) rv16[r][dvl] = pv[i];
    }
    if (wv == 0) {
      float gv = g_t[h * 4096 + bT + t0 + lane];
      float bv = beta_t[h * 4096 + bT + t0 + lane];
      float cum = gv;
#pragma unroll
      for (int off = 1; off < 64; off <<= 1) {
        float o = __shfl_up(cum, off);
        if (lane >= off) cum += o;
      }
      float tot = __shfl(cum, 63);
      garr[lane] = cum;
      earr[lane] = __expf(cum);
      warr[lane] = __expf(tot - cum) * bv;
      barr[lane] = bv;
      if (lane == 0) sdt = __expf(tot);
    }
    __syncthreads();  // B1
    if (ch + 1 < NCH) {
      LOADQK(t0 + CL);
      LOADV(t0 + CL);
    }
    // ---- v conv + silu -> fp16 transposed [dv][s]
    {
      int tl = tid >> 5;
#pragma unroll
      for (int rr = 0; rr < 4; ++rr) {
        int t = rr * 16 + tl;
        float a = cwv.x * h2f(rv16[t][dvl]) + cwv.y * h2f(rv16[t + 1][dvl]) +
                  cwv.z * h2f(rv16[t + 2][dvl]) + cwv.w * h2f(rv16[t + 3][dvl]);
        a = a * sigm(a);
        Vs[dvl][t] = f2h(a);
      }
    }
    // ---- A = Q K^T; this wave: rows m0..m0+15, col blocks nh*2, nh*2+1
    half8 a[4];
#pragma unroll
    for (int kk = 0; kk < 4; ++kk) a[kk] = *(half8*)&Qs[m0 + l15][l16 * 8 + kk * 32];
#pragma unroll
    for (int j = 0; j < 2; ++j) {
      int n = nh * 2 + j;
      f32x4 a4 = {};
#pragma unroll
      for (int kk = 0; kk < 4; ++kk) {
        half8 b8 = *(half8*)&Ks[n * 16 + l15][l16 * 8 + kk * 32];
        a4 = __builtin_amdgcn_mfma_f32_16x16x32_f16(a[kk], b8, a4, 0, 0, 0);
      }
      int col = n * 16 + l15;
      float gc = garr[col], bc = barr[col];
#pragma unroll
      for (int i = 0; i < 4; ++i) {
        int row = m0 + l16 * 4 + i;
        float cval = (col <= row) ? __expf(garr[row] - gc) * bc * a4[i] : 0.f;
        SIs[row][col] = f2h(cval);
      }
    }
    __syncthreads();  // B2
    // ---- out_inter = Q @ St_prev, scaled by e^{Gc[t]}
    f32x4 ao = {};
#pragma unroll
    for (int kk = 0; kk < 4; ++kk) {
      half8 s8 = *(half8*)&SH[p][nh * 16 + l15][l16 * 8 + kk * 32];
      ao = __builtin_amdgcn_mfma_f32_16x16x32_f16(a[kk], s8, ao, 0, 0, 0);
    }
#pragma unroll
    for (int i = 0; i < 4; ++i) ao[i] *= earr[m0 + l16 * 4 + i];
    // ---- out += SI @ V
#pragma unroll
    for (int kk = 0; kk < 2; ++kk) {
      half8 asi = *(half8*)&SIs[m0 + l15][l16 * 8 + kk * 32];
      half8 bv8 = *(half8*)&Vs[nh * 16 + l15][l16 * 8 + kk * 32];
      ao = __builtin_amdgcn_mfma_f32_16x16x32_f16(asi, bv8, ao, 0, 0, 0);
    }
#pragma unroll
    for (int i = 0; i < 4; ++i)
      outr[(size_t)(bT + t0 + m0 + l16 * 4 + i) * 4096 + vch + nh * 16 + l15] = ao[i];
    // ---- state update: St = sdt*St + V^T (K.w); this wave: dk band wv*16
#pragma unroll
    for (int m = 0; m < 2; ++m)
#pragma unroll
      for (int i = 0; i < 4; ++i) st[m][i] *= sdt;
#pragma unroll
    for (int kk = 0; kk < 2; ++kk) {
      half8 bw;
      {
        int dk = wv * 16 + l15;
#pragma unroll
        for (int e = 0; e < 8; ++e) {
          int s = l16 * 8 + e + kk * 32;
          bw[e] = (_Float16)(h2f(Ks[s][dk]) * warr[s]);
        }
      }
#pragma unroll
      for (int m = 0; m < 2; ++m) {
        half8 av = *(half8*)&Vs[m * 16 + l15][l16 * 8 + kk * 32];
        st[m] = __builtin_amdgcn_mfma_f32_16x16x32_f16(av, bw, st[m], 0, 0, 0);
      }
    }
#pragma unroll
    for (int m = 0; m < 2; ++m)
#pragma unroll
      for (int i = 0; i < 4; ++i)
        SH[p ^ 1][m * 16 + l16 * 4 + i][wv * 16 + l15] = f2h(st[m][i]);
    __syncthreads();  // B4
  }
}

// ---------------- per-(bt,head) RMS scale from f32 outr ----------------
__global__ __launch_bounds__(256) void k_rms(const float* __restrict__ outr, float* __restrict__ rms) {
  int pair = blockIdx.x * 4 + (threadIdx.x >> 6);
  int lane = threadIdx.x & 63;
  float2 v = *(const float2*)&outr[(size_t)pair * 128 + lane * 2];
  float ss = v.x * v.x + v.y * v.y;
#pragma unroll
  for (int m = 1; m < 64; m <<= 1) ss += __shfl_xor(ss, m);
  if (lane == 0) rms[pair] = rsqrtf(ss * (1.0f / 128.0f) + 1e-6f);
}

extern "C" void kernel_launch(void* const* d_in, const int* in_sizes, int n_in,
                              void* d_out, int out_size, void* d_ws, size_t ws_size,
                              hipStream_t stream) {
  const float* x = (const float*)d_in[0];
  // d_in[1] = positions (int64) — unused by the math
  const float* W_qkv = (const float*)d_in[2];
  const float* W_z = (const float*)d_in[3];
  const float* W_b = (const float*)d_in[4];
  const float* W_a = (const float*)d_in[5];
  const float* conv_w = (const float*)d_in[6];
  const float* dt_bias = (const float*)d_in[7];
  const float* A_log = (const float*)d_in[8];
  const float* norm_w = (const float*)d_in[9];
  const float* W_out = (const float*)d_in[10];
  float* out = (float*)d_out;

  const size_t MB = 1ull << 20;
  const size_t need = 192 * MB + 3 * (size_t)NBT * 32 * 4;  // == proven bound
  if (ws_size < need) {
    k_sentinel<<<1, 1, 0, stream>>>(out);
    return;
  }
  char* ws = (char*)d_ws;
  // Region A [0,64MB): xh | xl | xh16 | spare. Later: outr f32 (full). Later: wout16 [0,16).
  u16* xh = (u16*)ws;
  u16* xl = (u16*)(ws + 16 * MB);
  u16* xh16 = (u16*)(ws + 32 * MB);
  float* outr = (float*)ws;
  u16* wout16 = (u16*)ws;
  // Region B [64,128MB): early wba+babuf [64,67); qkA16 [96,128); qkB16 [64,96); om16 [96,128).
  u16* wbah = (u16*)(ws + 64 * MB);
  u16* wbal = (u16*)(ws + 64 * MB + 512 * 1024);
  float* babuf = (float*)(ws + 65 * MB);
  u16* qkB16 = (u16*)(ws + 64 * MB);
  u16* qkA16 = (u16*)(ws + 96 * MB);
  u16* om16 = (u16*)(ws + 96 * MB);
  // Region C [128,192MB): wsh16 full [128,160); v16 [160,192). Later xh16b [128,144), wz16 [144,160).
  u16* wsh16 = (u16*)(ws + 128 * MB);
  u16* v16 = (u16*)(ws + 160 * MB);
  u16* xh16b = (u16*)(ws + 128 * MB);
  u16* wz16 = (u16*)(ws + 144 * MB);
  float* beta_t = (float*)(ws + 192 * MB);
  float* g_t = beta_t + (size_t)NBT * 32;
  float* rmsb = g_t + (size_t)NBT * 32;

  const int N4X = NBT * NC / 4;
  // --- conversions + ba path ---
  k_cvtx<<<N4X / 256, 256, 0, stream>>>(x, xh, xl, xh16, N4X);
  k_cvt16<<<2 * N4X / 256, 256, 0, stream>>>(W_qkv, wsh16, 2 * N4X);  // full 8192 rows
  k_wba<<<128 * NC / 256, 256, 0, stream>>>(W_b, W_a, wbah, wbal);
  k_gemm_bf3<<<dim3(1, NBT / 128), 256, 0, stream>>>(xh, xl, wbah, wbal, babuf, NBT, 128, NC);
  k_bg<<<NBT * 32 / 256, 256, 0, stream>>>(babuf, dt_bias, A_log, beta_t, g_t);

  // --- qk projection (fp16, BK=64) -> conv+norm -> qkB16 ---
  k_gemm16<1><<<dim3(4096 / 128, NBT / 128), 256, 0, stream>>>(xh16, wsh16, qkA16, NBT, 4096, NC,
                                                               nullptr, nullptr, nullptr);
  k_convqk<<<NBT, 256, 0, stream>>>(qkA16, conv_w, qkB16);

  // --- v projection (fp16, BK=64) ---
  k_gemm16<1><<<dim3(4096 / 128, NBT / 128), 256, 0, stream>>>(xh16, wsh16 + (size_t)4096 * NC, v16,
                                                               NBT, 4096, NC, nullptr, nullptr, nullptr);

  // --- chunked scan -> outr (overlays x planes, dead) ---
  k_scanc<<<256, 512, 0, stream>>>(qkB16, v16, conv_w, beta_t, g_t, outr);
  k_rms<<<NBT * NHV / 4, 256, 0, stream>>>(outr, rmsb);

  // --- z projection (fp16, BK=64) with fused gate epilogue -> om16 (qkA16 dead) ---
  k_cvt16<<<N4X / 256, 256, 0, stream>>>(x, xh16b, N4X);
  k_cvt16<<<N4X / 256, 256, 0, stream>>>(W_z, wz16, N4X);
  k_gemm16<2><<<dim3(VALD / 128, NBT / 128), 256, 0, stream>>>(xh16b, wz16, om16, NBT, VALD, NC,
                                                               outr, rmsb, norm_w);

  // --- output projection (fp16, BK=64) -> f32 out (outr dead -> wout16 overlay) ---
  k_cvt16<<<N4X / 256, 256, 0, stream>>>(W_out, wout16, N4X);
  k_gemm16<0><<<dim3(NC / 128, NBT / 128), 256, 0, stream>>>(om16, wout16, out, NBT, NC, VALD,
                                                             nullptr, nullptr, nullptr);
}

// Round 18
// 709.040 us; speedup vs baseline: 1.1930x; 1.0596x over previous
//
#include <hip/hip_runtime.h>

typedef unsigned short u16;
typedef unsigned int u32;
typedef __attribute__((ext_vector_type(8))) short short8;
typedef __attribute__((ext_vector_type(8))) _Float16 half8;
typedef __attribute__((ext_vector_type(4))) float f32x4;

#define NB 2
#define NT 2048
#define NC 2048
#define NHV 32
#define VALD 4096
#define NBT 4096
#define CL 64
#define NCH (NT / CL)

#define GL16(gp, lp) __builtin_amdgcn_global_load_lds( \
    (const __attribute__((address_space(1))) unsigned int*)(gp), \
    (__attribute__((address_space(3))) unsigned int*)(lp), 16, 0, 0)

static __device__ __forceinline__ float bf2f(u16 u) {
  union { u32 u; float f; } x; x.u = ((u32)u) << 16; return x.f;
}
static __device__ __forceinline__ u16 f2bf(float f) {
  union { float f; u32 u; } x; x.f = f;
  u32 r = x.u + 0x7fffu + ((x.u >> 16) & 1u);
  return (u16)(r >> 16);
}
static __device__ __forceinline__ u16 f2h(float f) {
  union { _Float16 h; u16 u; } c; c.h = (_Float16)f; return c.u;
}
static __device__ __forceinline__ float h2f(u16 u) {
  union { u16 u; _Float16 h; } c; c.u = u; return (float)c.h;
}
static __device__ __forceinline__ float sigm(float x) { return 1.0f / (1.0f + __expf(-x)); }
static __device__ __forceinline__ int ldsoff(int row, int c8) {
  return row * 48 + ((c8 ^ ((row >> 2) & 3)) << 3);
}

// ---------------- sentinel ----------------
__global__ void k_sentinel(float* out) { out[0] = 1.0e6f; }

// ---------------- x -> bf16 hi/lo planes + fp16 plane (single read of x) ----------------
__global__ __launch_bounds__(256) void k_cvtx(const float* __restrict__ in, u16* __restrict__ hi,
                                              u16* __restrict__ lo, u16* __restrict__ h16, int n4) {
  int i = blockIdx.x * 256 + threadIdx.x;
  if (i >= n4) return;
  float4 v = ((const float4*)in)[i];
  ushort4 h, l, p;
  h.x = f2bf(v.x); l.x = f2bf(v.x - bf2f(h.x)); p.x = f2h(v.x);
  h.y = f2bf(v.y); l.y = f2bf(v.y - bf2f(h.y)); p.y = f2h(v.y);
  h.z = f2bf(v.z); l.z = f2bf(v.z - bf2f(h.z)); p.z = f2h(v.z);
  h.w = f2bf(v.w); l.w = f2bf(v.w - bf2f(h.w)); p.w = f2h(v.w);
  ((ushort4*)hi)[i] = h;
  ((ushort4*)lo)[i] = l;
  ((ushort4*)h16)[i] = p;
}

// ---------------- f32 -> fp16 plane ----------------
__global__ __launch_bounds__(256) void k_cvt16(const float* __restrict__ in, u16* __restrict__ out, int n4) {
  int i = blockIdx.x * 256 + threadIdx.x;
  if (i >= n4) return;
  float4 v = ((const float4*)in)[i];
  ushort4 o;
  o.x = f2h(v.x); o.y = f2h(v.y); o.z = f2h(v.z); o.w = f2h(v.w);
  ((ushort4*)out)[i] = o;
}

// ---------------- build padded W_ba hi/lo bf16 planes [128][2048] ----------------
__global__ __launch_bounds__(256) void k_wba(const float* __restrict__ Wb, const float* __restrict__ Wa,
                                             u16* __restrict__ hi, u16* __restrict__ lo) {
  int i = blockIdx.x * 256 + threadIdx.x;
  int r = i >> 11, c = i & 2047;
  float v = 0.f;
  if (r < 32) v = Wb[r * 2048 + c];
  else if (r < 64) v = Wa[(r - 32) * 2048 + c];
  u16 h = f2bf(v);
  hi[i] = h;
  lo[i] = f2bf(v - bf2f(h));
}

// ---------------- 3-pass bf16 GEMM (ba projection; recurrence-gate path) ----------------
__global__ __launch_bounds__(256) void k_gemm_bf3(const u16* __restrict__ Ahg, const u16* __restrict__ Alg,
                                                  const u16* __restrict__ Bhg, const u16* __restrict__ Blg,
                                                  float* __restrict__ C0, int M, int N, int K) {
  __shared__ __align__(16) u16 As_h[128 * 48];
  __shared__ __align__(16) u16 As_l[128 * 48];
  __shared__ __align__(16) u16 Bs_h[128 * 48];
  __shared__ __align__(16) u16 Bs_l[128 * 48];
  const int tid = threadIdx.x;
  const int lane = tid & 63, wave = tid >> 6;
  const int wr = wave >> 1, wc = wave & 1;
  const int l15 = lane & 15, l16 = lane >> 4;
  const int row0 = blockIdx.y * 128, col0 = blockIdx.x * 128;
  const int sr = tid >> 1, sk = (tid & 1) * 16;
  const int c0 = sk >> 3;
  const int w0 = ldsoff(sr, c0), w1 = ldsoff(sr, c0 + 1);
  f32x4 acc[4][4] = {};
  for (int k0 = 0; k0 < K; k0 += 32) {
    const size_t aoff = (size_t)(row0 + sr) * K + k0 + sk;
    const size_t boff = (size_t)(col0 + sr) * K + k0 + sk;
    *(short8*)&As_h[w0] = *(const short8*)&Ahg[aoff];
    *(short8*)&As_h[w1] = *(const short8*)&Ahg[aoff + 8];
    *(short8*)&As_l[w0] = *(const short8*)&Alg[aoff];
    *(short8*)&As_l[w1] = *(const short8*)&Alg[aoff + 8];
    *(short8*)&Bs_h[w0] = *(const short8*)&Bhg[boff];
    *(short8*)&Bs_h[w1] = *(const short8*)&Bhg[boff + 8];
    *(short8*)&Bs_l[w0] = *(const short8*)&Blg[boff];
    *(short8*)&Bs_l[w1] = *(const short8*)&Blg[boff + 8];
    __syncthreads();
    short8 ah[4], al[4], bh[4], bl[4];
#pragma unroll
    for (int mi = 0; mi < 4; ++mi) {
      int off = ldsoff(wr * 64 + mi * 16 + l15, l16);
      ah[mi] = *(short8*)&As_h[off];
      al[mi] = *(short8*)&As_l[off];
    }
#pragma unroll
    for (int ni = 0; ni < 4; ++ni) {
      int off = ldsoff(wc * 64 + ni * 16 + l15, l16);
      bh[ni] = *(short8*)&Bs_h[off];
      bl[ni] = *(short8*)&Bs_l[off];
    }
#pragma unroll
    for (int mi = 0; mi < 4; ++mi)
#pragma unroll
      for (int ni = 0; ni < 4; ++ni) {
        acc[mi][ni] = __builtin_amdgcn_mfma_f32_16x16x32_bf16(ah[mi], bh[ni], acc[mi][ni], 0, 0, 0);
        acc[mi][ni] = __builtin_amdgcn_mfma_f32_16x16x32_bf16(al[mi], bh[ni], acc[mi][ni], 0, 0, 0);
        acc[mi][ni] = __builtin_amdgcn_mfma_f32_16x16x32_bf16(ah[mi], bl[ni], acc[mi][ni], 0, 0, 0);
      }
    __syncthreads();
  }
#pragma unroll
  for (int mi = 0; mi < 4; ++mi)
#pragma unroll
    for (int ni = 0; ni < 4; ++ni) {
      int rr = row0 + wr * 64 + mi * 16 + l16 * 4;
      int cc = col0 + wc * 64 + ni * 16 + l15;
#pragma unroll
      for (int i = 0; i < 4; ++i)
        C0[(size_t)(rr + i) * N + cc] = acc[mi][ni][i];
    }
}

// ---------------- single-pass fp16 GEMM, 128x128 tile, BK=64, global_load_lds staging ----------------
// LDS linear [128][64] u16 per matrix; global source chunk pre-swizzled cg = (lane&7)^(row&7);
// fragment reads apply same XOR. (Staging/swizzle pattern correctness-proven in r10.)
// MODE 0: f32 out. MODE 1: fp16 out. MODE 2: z epilogue -> fp16 out.
template <int MODE>
__global__ __launch_bounds__(256) void k_gemm16(const u16* __restrict__ Ag, const u16* __restrict__ Bg,
                                                void* __restrict__ C0, int M, int N, int K,
                                                const float* __restrict__ e0, const float* __restrict__ e1,
                                                const float* __restrict__ e2) {
  __shared__ __align__(16) u16 As[128 * 64];
  __shared__ __align__(16) u16 Bs[128 * 64];
  const int tid = threadIdx.x;
  const int lane = tid & 63, wave = tid >> 6;
  const int wr = wave >> 1, wc = wave & 1;
  const int l15 = lane & 15, l16 = lane >> 4;
  const int row0 = blockIdx.y * 128, col0 = blockIdx.x * 128;
  // staging maps: per matrix 4 gload_lds per wave; instr i covers rows wave*32+i*8 .. +8
  u32 gA[4], gB[4], lofs[4];
#pragma unroll
  for (int i = 0; i < 4; ++i) {
    int o = wave * 2048 + i * 512 + lane * 8;        // element offset (linear LDS)
    int row = o >> 6;
    int cg = ((lane & 7) ^ (row & 7)) * 8;           // pre-swizzled global k-chunk
    gA[i] = (u32)(row0 + row) * (u32)K + cg;
    gB[i] = (u32)(col0 + row) * (u32)K + cg;
    lofs[i] = (u32)(wave * 2048 + i * 512);          // wave-uniform LDS base
  }
  f32x4 acc[4][4] = {};
  for (int k0 = 0; k0 < K; k0 += 64) {
#pragma unroll
    for (int i = 0; i < 4; ++i) {
      GL16(Ag + gA[i] + k0, &As[lofs[i]]);
      GL16(Bg + gB[i] + k0, &Bs[lofs[i]]);
    }
    __syncthreads();  // compiler drains vmcnt before barrier (m97 semantics)
#pragma unroll
    for (int kk = 0; kk < 2; ++kk) {
      half8 a[4], b[4];
#pragma unroll
      for (int mi = 0; mi < 4; ++mi) {
        int row = wr * 64 + mi * 16 + l15;
        a[mi] = *(half8*)&As[row * 64 + (((kk * 4 + l16) ^ (l15 & 7)) << 3)];
      }
#pragma unroll
      for (int ni = 0; ni < 4; ++ni) {
        int row = wc * 64 + ni * 16 + l15;
        b[ni] = *(half8*)&Bs[row * 64 + (((kk * 4 + l16) ^ (l15 & 7)) << 3)];
      }
#pragma unroll
      for (int mi = 0; mi < 4; ++mi)
#pragma unroll
        for (int ni = 0; ni < 4; ++ni)
          acc[mi][ni] = __builtin_amdgcn_mfma_f32_16x16x32_f16(a[mi], b[ni], acc[mi][ni], 0, 0, 0);
    }
    __syncthreads();
  }
#pragma unroll
  for (int mi = 0; mi < 4; ++mi) {
#pragma unroll
    for (int ni = 0; ni < 4; ++ni) {
      int rr = row0 + wr * 64 + mi * 16 + l16 * 4;
      int cc = col0 + wc * 64 + ni * 16 + l15;
#pragma unroll
      for (int i = 0; i < 4; ++i) {
        float v = acc[mi][ni][i];
        size_t idx = (size_t)(rr + i) * N + cc;
        if constexpr (MODE == 0) {
          ((float*)C0)[idx] = v;
        } else if constexpr (MODE == 1) {
          ((u16*)C0)[idx] = f2h(v);
        } else {
          float zs = v * sigm(v);
          float o = e0[idx] * e1[(size_t)(rr + i) * 32 + (cc >> 7)] * e2[cc & 127] * zs;
          ((u16*)C0)[idx] = f2h(o);
        }
      }
    }
  }
}

// ---------------- beta / g from ba [BT,128] f32, TRANSPOSED out [32][4096] ----------------
__global__ __launch_bounds__(256) void k_bg(const float* __restrict__ ba, const float* __restrict__ dt_bias,
                                            const float* __restrict__ A_log, float* __restrict__ beta_t,
                                            float* __restrict__ g_t) {
  int i = blockIdx.x * 256 + threadIdx.x;
  int bt = i >> 5, h = i & 31;
  float bv = ba[(size_t)bt * 128 + h];
  float av = ba[(size_t)bt * 128 + 32 + h];
  beta_t[h * 4096 + bt] = sigm(bv);
  float xx = av + dt_bias[h];
  float sp = (xx > 20.f) ? xx : log1pf(__expf(xx));
  g_t[h * 4096 + bt] = -__expf(A_log[h]) * sp;
}

// ---------------- conv+SiLU+L2norm for q,k: fp16 in [4096][4096] -> fp16 out ----------------
__global__ __launch_bounds__(256) void k_convqk(const u16* __restrict__ qkraw, const float* __restrict__ cw,
                                                u16* __restrict__ qkn) {
  __shared__ float sval[4096];
  __shared__ float snrm[32];
  const int tid = threadIdx.x;
  const int bt = blockIdx.x;
  const int b = bt >> 11, t = bt & 2047;
  for (int i = 0; i < 16; ++i) {
    int c = i * 256 + tid;
    float acc = 0.f;
#pragma unroll
    for (int j = 0; j < 4; ++j) {
      int ts = t - 3 + j;
      if (ts >= 0) acc += cw[c * 4 + j] * h2f(qkraw[(size_t)(b * 2048 + ts) * 4096 + c]);
    }
    sval[c] = acc * sigm(acc);
  }
  __syncthreads();
  {
    int gidx = tid >> 3, s = tid & 7;
    float ss = 0.f;
#pragma unroll
    for (int i2 = 0; i2 < 16; ++i2) { float v = sval[gidx * 128 + s * 16 + i2]; ss += v * v; }
    ss += __shfl_xor(ss, 1); ss += __shfl_xor(ss, 2); ss += __shfl_xor(ss, 4);
    if (s == 0) snrm[gidx] = 1.0f / fmaxf(sqrtf(ss), 1e-12f);
  }
  __syncthreads();
  for (int i = 0; i < 16; ++i) {
    int c = i * 256 + tid;
    qkn[(size_t)bt * 4096 + c] = f2h(sval[c] * snrm[c >> 7]);
  }
}

// ---------------- chunked gated-linear-attention scan, single-fp16 MFMA ----------------
// grid 256 = dq(4) x h(32) x b(2); block 512 (8 waves); ~71 KB LDS -> 2 blocks/CU.
__global__ __launch_bounds__(512, 4) void k_scanc(const u16* __restrict__ qk16, const u16* __restrict__ v16,
                                                  const float* __restrict__ cw,
                                                  const float* __restrict__ beta_t, const float* __restrict__ g_t,
                                                  float* __restrict__ outr) {
  __shared__ __align__(16) u16 Qs[64][136], Ks[64][136];
  __shared__ __align__(16) u16 Vs[32][72];
  __shared__ __align__(16) u16 SIs[64][72];
  __shared__ __align__(16) u16 SH[2][32][132];
  __shared__ u16 rv16[67][36];
  __shared__ float garr[64], barr[64], warr[64], earr[64];
  __shared__ float sdt;

  const int tid = threadIdx.x;
  const int lane = tid & 63, wv = tid >> 6;
  const int l15 = lane & 15, l16 = lane >> 4;
  const int dq = blockIdx.x & 3, h = (blockIdx.x >> 2) & 31, b = blockIdx.x >> 7;
  const int bT = b * 2048;
  const int hk = h >> 1;
  const int dvl = tid & 31;
  const int vch = h * 128 + dq * 32;
  const float4 cwv = *(const float4*)&cw[(4096 + vch + dvl) * 4];
  const int mblk = wv & 3, nh = wv >> 2;
  const int m0 = mblk * 16;
  const int sr = tid >> 3, d0 = (tid & 7) * 16;
  const int r0v = tid >> 5;

  for (int i = tid; i < 2 * 32 * 132; i += 512) ((u16*)SH)[i] = 0;
  f32x4 st[2] = {};

  short8 pq[2], pk[2];
  u16 pv[5];
  auto LOADQK = [&](int t0) {
    const size_t base = (size_t)(bT + t0 + sr) * 4096 + hk * 128 + d0;
    pq[0] = *(const short8*)&qk16[base];        pq[1] = *(const short8*)&qk16[base + 8];
    pk[0] = *(const short8*)&qk16[base + 2048]; pk[1] = *(const short8*)&qk16[base + 2056];
  };
  auto LOADV = [&](int t0) {
#pragma unroll
    for (int i = 0; i < 5; ++i) {
      int r = r0v + i * 16;
      int tr = t0 - 3 + r;
      pv[i] = (r < 67 && tr >= 0) ? v16[(size_t)(bT + tr) * 4096 + vch + dvl] : (u16)0;
    }
  };

  LOADQK(0);
  LOADV(0);

  for (int ch = 0; ch < NCH; ++ch) {
    const int t0 = ch * CL;
    const int p = ch & 1;
    *(short8*)&Qs[sr][d0] = pq[0]; *(short8*)&Qs[sr][d0 + 8] = pq[1];
    *(short8*)&Ks[sr][d0] = pk[0]; *(short8*)&Ks[sr][d0 + 8] = pk[1];
#pragma unroll
    for (int i = 0; i < 5; ++i) {
      int r = r0v + i * 16;
      if (r < 67) rv16[r][dvl] = pv[i];
    }
    if (wv == 0) {
      float gv = g_t[h * 4096 + bT + t0 + lane];
      float bv = beta_t[h * 4096 + bT + t0 + lane];
      float cum = gv;
#pragma unroll
      for (int off = 1; off < 64; off <<= 1) {
        float o = __shfl_up(cum, off);
        if (lane >= off) cum += o;
      }
      float tot = __shfl(cum, 63);
      garr[lane] = cum;
      earr[lane] = __expf(cum);
      warr[lane] = __expf(tot - cum) * bv;
      barr[lane] = bv;
      if (lane == 0) sdt = __expf(tot);
    }
    __syncthreads();  // B1
    if (ch + 1 < NCH) {
      LOADQK(t0 + CL);
      LOADV(t0 + CL);
    }
    // ---- v conv + silu -> fp16 transposed [dv][s]
    {
      int tl = tid >> 5;
#pragma unroll
      for (int rr = 0; rr < 4; ++rr) {
        int t = rr * 16 + tl;
        float a = cwv.x * h2f(rv16[t][dvl]) + cwv.y * h2f(rv16[t + 1][dvl]) +
                  cwv.z * h2f(rv16[t + 2][dvl]) + cwv.w * h2f(rv16[t + 3][dvl]);
        a = a * sigm(a);
        Vs[dvl][t] = f2h(a);
      }
    }
    // ---- A = Q K^T; this wave: rows m0..m0+15, col blocks nh*2, nh*2+1
    half8 a[4];
#pragma unroll
    for (int kk = 0; kk < 4; ++kk) a[kk] = *(half8*)&Qs[m0 + l15][l16 * 8 + kk * 32];
#pragma unroll
    for (int j = 0; j < 2; ++j) {
      int n = nh * 2 + j;
      f32x4 a4 = {};
#pragma unroll
      for (int kk = 0; kk < 4; ++kk) {
        half8 b8 = *(half8*)&Ks[n * 16 + l15][l16 * 8 + kk * 32];
        a4 = __builtin_amdgcn_mfma_f32_16x16x32_f16(a[kk], b8, a4, 0, 0, 0);
      }
      int col = n * 16 + l15;
      float gc = garr[col], bc = barr[col];
#pragma unroll
      for (int i = 0; i < 4; ++i) {
        int row = m0 + l16 * 4 + i;
        float cval = (col <= row) ? __expf(garr[row] - gc) * bc * a4[i] : 0.f;
        SIs[row][col] = f2h(cval);
      }
    }
    __syncthreads();  // B2
    // ---- out_inter = Q @ St_prev, scaled by e^{Gc[t]}
    f32x4 ao = {};
#pragma unroll
    for (int kk = 0; kk < 4; ++kk) {
      half8 s8 = *(half8*)&SH[p][nh * 16 + l15][l16 * 8 + kk * 32];
      ao = __builtin_amdgcn_mfma_f32_16x16x32_f16(a[kk], s8, ao, 0, 0, 0);
    }
#pragma unroll
    for (int i = 0; i < 4; ++i) ao[i] *= earr[m0 + l16 * 4 + i];
    // ---- out += SI @ V
#pragma unroll
    for (int kk = 0; kk < 2; ++kk) {
      half8 asi = *(half8*)&SIs[m0 + l15][l16 * 8 + kk * 32];
      half8 bv8 = *(half8*)&Vs[nh * 16 + l15][l16 * 8 + kk * 32];
      ao = __builtin_amdgcn_mfma_f32_16x16x32_f16(asi, bv8, ao, 0, 0, 0);
    }
#pragma unroll
    for (int i = 0; i < 4; ++i)
      outr[(size_t)(bT + t0 + m0 + l16 * 4 + i) * 4096 + vch + nh * 16 + l15] = ao[i];
    // ---- state update: St = sdt*St + V^T (K.w); this wave: dk band wv*16
#pragma unroll
    for (int m = 0; m < 2; ++m)
#pragma unroll
      for (int i = 0; i < 4; ++i) st[m][i] *= sdt;
#pragma unroll
    for (int kk = 0; kk < 2; ++kk) {
      half8 bw;
      {
        int dk = wv * 16 + l15;
#pragma unroll
        for (int e = 0; e < 8; ++e) {
          int s = l16 * 8 + e + kk * 32;
          bw[e] = (_Float16)(h2f(Ks[s][dk]) * warr[s]);
        }
      }
#pragma unroll
      for (int m = 0; m < 2; ++m) {
        half8 av = *(half8*)&Vs[m * 16 + l15][l16 * 8 + kk * 32];
        st[m] = __builtin_amdgcn_mfma_f32_16x16x32_f16(av, bw, st[m], 0, 0, 0);
      }
    }
#pragma unroll
    for (int m = 0; m < 2; ++m)
#pragma unroll
      for (int i = 0; i < 4; ++i)
        SH[p ^ 1][m * 16 + l16 * 4 + i][wv * 16 + l15] = f2h(st[m][i]);
    __syncthreads();  // B4
  }
}

// ---------------- per-(bt,head) RMS scale from f32 outr ----------------
__global__ __launch_bounds__(256) void k_rms(const float* __restrict__ outr, float* __restrict__ rms) {
  int pair = blockIdx.x * 4 + (threadIdx.x >> 6);
  int lane = threadIdx.x & 63;
  float2 v = *(const float2*)&outr[(size_t)pair * 128 + lane * 2];
  float ss = v.x * v.x + v.y * v.y;
#pragma unroll
  for (int m = 1; m < 64; m <<= 1) ss += __shfl_xor(ss, m);
  if (lane == 0) rms[pair] = rsqrtf(ss * (1.0f / 128.0f) + 1e-6f);
}

extern "C" void kernel_launch(void* const* d_in, const int* in_sizes, int n_in,
                              void* d_out, int out_size, void* d_ws, size_t ws_size,
                              hipStream_t stream) {
  const float* x = (const float*)d_in[0];
  // d_in[1] = positions (int64) — unused by the math
  const float* W_qkv = (const float*)d_in[2];
  const float* W_z = (const float*)d_in[3];
  const float* W_b = (const float*)d_in[4];
  const float* W_a = (const float*)d_in[5];
  const float* conv_w = (const float*)d_in[6];
  const float* dt_bias = (const float*)d_in[7];
  const float* A_log = (const float*)d_in[8];
  const float* norm_w = (const float*)d_in[9];
  const float* W_out = (const float*)d_in[10];
  float* out = (float*)d_out;

  const size_t MB = 1ull << 20;
  const size_t need = 192 * MB + 3 * (size_t)NBT * 32 * 4;  // == proven bound
  if (ws_size < need) {
    k_sentinel<<<1, 1, 0, stream>>>(out);
    return;
  }
  char* ws = (char*)d_ws;
  // Region A [0,64MB): xh | xl | xh16 | spare. Later: outr f32 (full). Later: wout16 [0,16).
  u16* xh = (u16*)ws;
  u16* xl = (u16*)(ws + 16 * MB);
  u16* xh16 = (u16*)(ws + 32 * MB);
  float* outr = (float*)ws;
  u16* wout16 = (u16*)ws;
  // Region B [64,128MB): early wba+babuf [64,67); qkA16 [96,128); qkB16 [64,96); om16 [96,128).
  u16* wbah = (u16*)(ws + 64 * MB);
  u16* wbal = (u16*)(ws + 64 * MB + 512 * 1024);
  float* babuf = (float*)(ws + 65 * MB);
  u16* qkB16 = (u16*)(ws + 64 * MB);
  u16* qkA16 = (u16*)(ws + 96 * MB);
  u16* om16 = (u16*)(ws + 96 * MB);
  // Region C [128,192MB): wsh16 full [128,160); v16 [160,192). Later xh16b [128,144), wz16 [144,160).
  u16* wsh16 = (u16*)(ws + 128 * MB);
  u16* v16 = (u16*)(ws + 160 * MB);
  u16* xh16b = (u16*)(ws + 128 * MB);
  u16* wz16 = (u16*)(ws + 144 * MB);
  float* beta_t = (float*)(ws + 192 * MB);
  float* g_t = beta_t + (size_t)NBT * 32;
  float* rmsb = g_t + (size_t)NBT * 32;

  const int N4X = NBT * NC / 4;
  // --- conversions + ba path ---
  k_cvtx<<<N4X / 256, 256, 0, stream>>>(x, xh, xl, xh16, N4X);
  k_cvt16<<<2 * N4X / 256, 256, 0, stream>>>(W_qkv, wsh16, 2 * N4X);  // full 8192 rows
  k_wba<<<128 * NC / 256, 256, 0, stream>>>(W_b, W_a, wbah, wbal);
  k_gemm_bf3<<<dim3(1, NBT / 128), 256, 0, stream>>>(xh, xl, wbah, wbal, babuf, NBT, 128, NC);
  k_bg<<<NBT * 32 / 256, 256, 0, stream>>>(babuf, dt_bias, A_log, beta_t, g_t);

  // --- qk projection (fp16, gload_lds) -> conv+norm -> qkB16 ---
  k_gemm16<1><<<dim3(4096 / 128, NBT / 128), 256, 0, stream>>>(xh16, wsh16, qkA16, NBT, 4096, NC,
                                                               nullptr, nullptr, nullptr);
  k_convqk<<<NBT, 256, 0, stream>>>(qkA16, conv_w, qkB16);

  // --- v projection (fp16, gload_lds) ---
  k_gemm16<1><<<dim3(4096 / 128, NBT / 128), 256, 0, stream>>>(xh16, wsh16 + (size_t)4096 * NC, v16,
                                                               NBT, 4096, NC, nullptr, nullptr, nullptr);

  // --- chunked scan -> outr (overlays x planes, dead) ---
  k_scanc<<<256, 512, 0, stream>>>(qkB16, v16, conv_w, beta_t, g_t, outr);
  k_rms<<<NBT * NHV / 4, 256, 0, stream>>>(outr, rmsb);

  // --- z projection (fp16, gload_lds) with fused gate epilogue -> om16 (qkA16 dead) ---
  k_cvt16<<<N4X / 256, 256, 0, stream>>>(x, xh16b, N4X);
  k_cvt16<<<N4X / 256, 256, 0, stream>>>(W_z, wz16, N4X);
  k_gemm16<2><<<dim3(VALD / 128, NBT / 128), 256, 0, stream>>>(xh16b, wz16, om16, NBT, VALD, NC,
                                                               outr, rmsb, norm_w);

  // --- output projection (fp16, gload_lds) -> f32 out (outr dead -> wout16 overlay) ---
  k_cvt16<<<N4X / 256, 256, 0, stream>>>(W_out, wout16, N4X);
  k_gemm16<0><<<dim3(NC / 128, NBT / 128), 256, 0, stream>>>(om16, wout16, out, NBT, NC, VALD,
                                                             nullptr, nullptr, nullptr);
}

// Round 19
// 657.563 us; speedup vs baseline: 1.2863x; 1.0783x over previous
//
#include <hip/hip_runtime.h>

typedef unsigned short u16;
typedef unsigned int u32;
typedef __attribute__((ext_vector_type(8))) short short8;
typedef __attribute__((ext_vector_type(8))) _Float16 half8;
typedef __attribute__((ext_vector_type(4))) float f32x4;

#define NB 2
#define NT 2048
#define NC 2048
#define NHV 32
#define VALD 4096
#define NBT 4096
#define CL 64
#define NCH (NT / CL)

#define GL16(gp, lp) __builtin_amdgcn_global_load_lds( \
    (const __attribute__((address_space(1))) unsigned int*)(gp), \
    (__attribute__((address_space(3))) unsigned int*)(lp), 16, 0, 0)

static __device__ __forceinline__ float bf2f(u16 u) {
  union { u32 u; float f; } x; x.u = ((u32)u) << 16; return x.f;
}
static __device__ __forceinline__ u16 f2bf(float f) {
  union { float f; u32 u; } x; x.f = f;
  u32 r = x.u + 0x7fffu + ((x.u >> 16) & 1u);
  return (u16)(r >> 16);
}
static __device__ __forceinline__ u16 f2h(float f) {
  union { _Float16 h; u16 u; } c; c.h = (_Float16)f; return c.u;
}
static __device__ __forceinline__ float h2f(u16 u) {
  union { u16 u; _Float16 h; } c; c.u = u; return (float)c.h;
}
static __device__ __forceinline__ float sigm(float x) { return 1.0f / (1.0f + __expf(-x)); }
static __device__ __forceinline__ int ldsoff(int row, int c8) {
  return row * 48 + ((c8 ^ ((row >> 2) & 3)) << 3);
}

// ---------------- sentinel ----------------
__global__ void k_sentinel(float* out) { out[0] = 1.0e6f; }

// ---------------- x -> bf16 hi/lo planes + fp16 plane (single read of x) ----------------
__global__ __launch_bounds__(256) void k_cvtx(const float* __restrict__ in, u16* __restrict__ hi,
                                              u16* __restrict__ lo, u16* __restrict__ h16, int n4) {
  int i = blockIdx.x * 256 + threadIdx.x;
  if (i >= n4) return;
  float4 v = ((const float4*)in)[i];
  ushort4 h, l, p;
  h.x = f2bf(v.x); l.x = f2bf(v.x - bf2f(h.x)); p.x = f2h(v.x);
  h.y = f2bf(v.y); l.y = f2bf(v.y - bf2f(h.y)); p.y = f2h(v.y);
  h.z = f2bf(v.z); l.z = f2bf(v.z - bf2f(h.z)); p.z = f2h(v.z);
  h.w = f2bf(v.w); l.w = f2bf(v.w - bf2f(h.w)); p.w = f2h(v.w);
  ((ushort4*)hi)[i] = h;
  ((ushort4*)lo)[i] = l;
  ((ushort4*)h16)[i] = p;
}

// ---------------- f32 -> fp16 plane ----------------
__global__ __launch_bounds__(256) void k_cvt16(const float* __restrict__ in, u16* __restrict__ out, int n4) {
  int i = blockIdx.x * 256 + threadIdx.x;
  if (i >= n4) return;
  float4 v = ((const float4*)in)[i];
  ushort4 o;
  o.x = f2h(v.x); o.y = f2h(v.y); o.z = f2h(v.z); o.w = f2h(v.w);
  ((ushort4*)out)[i] = o;
}

// ---------------- build padded W_ba hi/lo bf16 planes [128][2048] ----------------
__global__ __launch_bounds__(256) void k_wba(const float* __restrict__ Wb, const float* __restrict__ Wa,
                                             u16* __restrict__ hi, u16* __restrict__ lo) {
  int i = blockIdx.x * 256 + threadIdx.x;
  int r = i >> 11, c = i & 2047;
  float v = 0.f;
  if (r < 32) v = Wb[r * 2048 + c];
  else if (r < 64) v = Wa[(r - 32) * 2048 + c];
  u16 h = f2bf(v);
  hi[i] = h;
  lo[i] = f2bf(v - bf2f(h));
}

// ---------------- 3-pass bf16 GEMM (ba projection; recurrence-gate path) ----------------
__global__ __launch_bounds__(256) void k_gemm_bf3(const u16* __restrict__ Ahg, const u16* __restrict__ Alg,
                                                  const u16* __restrict__ Bhg, const u16* __restrict__ Blg,
                                                  float* __restrict__ C0, int M, int N, int K) {
  __shared__ __align__(16) u16 As_h[128 * 48];
  __shared__ __align__(16) u16 As_l[128 * 48];
  __shared__ __align__(16) u16 Bs_h[128 * 48];
  __shared__ __align__(16) u16 Bs_l[128 * 48];
  const int tid = threadIdx.x;
  const int lane = tid & 63, wave = tid >> 6;
  const int wr = wave >> 1, wc = wave & 1;
  const int l15 = lane & 15, l16 = lane >> 4;
  const int row0 = blockIdx.y * 128, col0 = blockIdx.x * 128;
  const int sr = tid >> 1, sk = (tid & 1) * 16;
  const int c0 = sk >> 3;
  const int w0 = ldsoff(sr, c0), w1 = ldsoff(sr, c0 + 1);
  f32x4 acc[4][4] = {};
  for (int k0 = 0; k0 < K; k0 += 32) {
    const size_t aoff = (size_t)(row0 + sr) * K + k0 + sk;
    const size_t boff = (size_t)(col0 + sr) * K + k0 + sk;
    *(short8*)&As_h[w0] = *(const short8*)&Ahg[aoff];
    *(short8*)&As_h[w1] = *(const short8*)&Ahg[aoff + 8];
    *(short8*)&As_l[w0] = *(const short8*)&Alg[aoff];
    *(short8*)&As_l[w1] = *(const short8*)&Alg[aoff + 8];
    *(short8*)&Bs_h[w0] = *(const short8*)&Bhg[boff];
    *(short8*)&Bs_h[w1] = *(const short8*)&Bhg[boff + 8];
    *(short8*)&Bs_l[w0] = *(const short8*)&Blg[boff];
    *(short8*)&Bs_l[w1] = *(const short8*)&Blg[boff + 8];
    __syncthreads();
    short8 ah[4], al[4], bh[4], bl[4];
#pragma unroll
    for (int mi = 0; mi < 4; ++mi) {
      int off = ldsoff(wr * 64 + mi * 16 + l15, l16);
      ah[mi] = *(short8*)&As_h[off];
      al[mi] = *(short8*)&As_l[off];
    }
#pragma unroll
    for (int ni = 0; ni < 4; ++ni) {
      int off = ldsoff(wc * 64 + ni * 16 + l15, l16);
      bh[ni] = *(short8*)&Bs_h[off];
      bl[ni] = *(short8*)&Bs_l[off];
    }
#pragma unroll
    for (int mi = 0; mi < 4; ++mi)
#pragma unroll
      for (int ni = 0; ni < 4; ++ni) {
        acc[mi][ni] = __builtin_amdgcn_mfma_f32_16x16x32_bf16(ah[mi], bh[ni], acc[mi][ni], 0, 0, 0);
        acc[mi][ni] = __builtin_amdgcn_mfma_f32_16x16x32_bf16(al[mi], bh[ni], acc[mi][ni], 0, 0, 0);
        acc[mi][ni] = __builtin_amdgcn_mfma_f32_16x16x32_bf16(ah[mi], bl[ni], acc[mi][ni], 0, 0, 0);
      }
    __syncthreads();
  }
#pragma unroll
  for (int mi = 0; mi < 4; ++mi)
#pragma unroll
    for (int ni = 0; ni < 4; ++ni) {
      int rr = row0 + wr * 64 + mi * 16 + l16 * 4;
      int cc = col0 + wc * 64 + ni * 16 + l15;
#pragma unroll
      for (int i = 0; i < 4; ++i)
        C0[(size_t)(rr + i) * N + cc] = acc[mi][ni][i];
    }
}

// ---------------- single-pass fp16 GEMM, 128x128 tile, BK=64, gload_lds + LDS double buffer ------
// One barrier per K-tile: sync -> prefetch(t+1, buf^1) -> MFMA(t, buf).
// MODE 0: f32 out. MODE 1: fp16 out. MODE 2: z epilogue (e0 fp16) -> fp16 out.
template <int MODE>
__global__ __launch_bounds__(256) void k_gemm16(const u16* __restrict__ Ag, const u16* __restrict__ Bg,
                                                void* __restrict__ C0, int M, int N, int K,
                                                const u16* __restrict__ e0, const float* __restrict__ e1,
                                                const float* __restrict__ e2) {
  __shared__ __align__(16) u16 As[2 * 128 * 64];
  __shared__ __align__(16) u16 Bs[2 * 128 * 64];
  const int tid = threadIdx.x;
  const int lane = tid & 63, wave = tid >> 6;
  const int wr = wave >> 1, wc = wave & 1;
  const int l15 = lane & 15, l16 = lane >> 4;
  const int row0 = blockIdx.y * 128, col0 = blockIdx.x * 128;
  // staging maps: per matrix 4 gload_lds per wave; instr i covers rows wave*32+i*8 .. +8
  u32 gA[4], gB[4], lofs[4];
#pragma unroll
  for (int i = 0; i < 4; ++i) {
    int o = wave * 2048 + i * 512 + lane * 8;        // element offset (linear LDS)
    int row = o >> 6;
    int cg = ((lane & 7) ^ (row & 7)) * 8;           // pre-swizzled global k-chunk
    gA[i] = (u32)(row0 + row) * (u32)K + cg;
    gB[i] = (u32)(col0 + row) * (u32)K + cg;
    lofs[i] = (u32)(wave * 2048 + i * 512);          // wave-uniform LDS base
  }
  f32x4 acc[4][4] = {};
  const int NTILE = K >> 6;
  // prologue: stage tile 0 into buf 0
#pragma unroll
  for (int i = 0; i < 4; ++i) {
    GL16(Ag + gA[i], &As[lofs[i]]);
    GL16(Bg + gB[i], &Bs[lofs[i]]);
  }
  for (int t = 0; t < NTILE; ++t) {
    const u32 cb = (u32)(t & 1) * 8192;
    __syncthreads();  // drains vmcnt (tile t staged) + lgkm (prev reads done)
    if (t + 1 < NTILE) {
      const u32 nb = cb ^ 8192;
      const int kn = (t + 1) << 6;
#pragma unroll
      for (int i = 0; i < 4; ++i) {
        GL16(Ag + gA[i] + kn, &As[nb + lofs[i]]);
        GL16(Bg + gB[i] + kn, &Bs[nb + lofs[i]]);
      }
    }
#pragma unroll
    for (int kk = 0; kk < 2; ++kk) {
      half8 a[4], b[4];
#pragma unroll
      for (int mi = 0; mi < 4; ++mi) {
        int row = wr * 64 + mi * 16 + l15;
        a[mi] = *(half8*)&As[cb + row * 64 + (((kk * 4 + l16) ^ (l15 & 7)) << 3)];
      }
#pragma unroll
      for (int ni = 0; ni < 4; ++ni) {
        int row = wc * 64 + ni * 16 + l15;
        b[ni] = *(half8*)&Bs[cb + row * 64 + (((kk * 4 + l16) ^ (l15 & 7)) << 3)];
      }
#pragma unroll
      for (int mi = 0; mi < 4; ++mi)
#pragma unroll
        for (int ni = 0; ni < 4; ++ni)
          acc[mi][ni] = __builtin_amdgcn_mfma_f32_16x16x32_f16(a[mi], b[ni], acc[mi][ni], 0, 0, 0);
    }
  }
#pragma unroll
  for (int mi = 0; mi < 4; ++mi) {
#pragma unroll
    for (int ni = 0; ni < 4; ++ni) {
      int rr = row0 + wr * 64 + mi * 16 + l16 * 4;
      int cc = col0 + wc * 64 + ni * 16 + l15;
#pragma unroll
      for (int i = 0; i < 4; ++i) {
        float v = acc[mi][ni][i];
        size_t idx = (size_t)(rr + i) * N + cc;
        if constexpr (MODE == 0) {
          ((float*)C0)[idx] = v;
        } else if constexpr (MODE == 1) {
          ((u16*)C0)[idx] = f2h(v);
        } else {
          float zs = v * sigm(v);
          float o = h2f(e0[idx]) * e1[(size_t)(rr + i) * 32 + (cc >> 7)] * e2[cc & 127] * zs;
          ((u16*)C0)[idx] = f2h(o);
        }
      }
    }
  }
}

// ---------------- beta / g from ba [BT,128] f32, TRANSPOSED out [32][4096] ----------------
__global__ __launch_bounds__(256) void k_bg(const float* __restrict__ ba, const float* __restrict__ dt_bias,
                                            const float* __restrict__ A_log, float* __restrict__ beta_t,
                                            float* __restrict__ g_t) {
  int i = blockIdx.x * 256 + threadIdx.x;
  int bt = i >> 5, h = i & 31;
  float bv = ba[(size_t)bt * 128 + h];
  float av = ba[(size_t)bt * 128 + 32 + h];
  beta_t[h * 4096 + bt] = sigm(bv);
  float xx = av + dt_bias[h];
  float sp = (xx > 20.f) ? xx : log1pf(__expf(xx));
  g_t[h * 4096 + bt] = -__expf(A_log[h]) * sp;
}

// ---------------- conv+SiLU+L2norm for q,k: fp16 in [4096][4096] -> fp16 out ----------------
__global__ __launch_bounds__(256) void k_convqk(const u16* __restrict__ qkraw, const float* __restrict__ cw,
                                                u16* __restrict__ qkn) {
  __shared__ float sval[4096];
  __shared__ float snrm[32];
  const int tid = threadIdx.x;
  const int bt = blockIdx.x;
  const int b = bt >> 11, t = bt & 2047;
  for (int i = 0; i < 16; ++i) {
    int c = i * 256 + tid;
    float acc = 0.f;
#pragma unroll
    for (int j = 0; j < 4; ++j) {
      int ts = t - 3 + j;
      if (ts >= 0) acc += cw[c * 4 + j] * h2f(qkraw[(size_t)(b * 2048 + ts) * 4096 + c]);
    }
    sval[c] = acc * sigm(acc);
  }
  __syncthreads();
  {
    int gidx = tid >> 3, s = tid & 7;
    float ss = 0.f;
#pragma unroll
    for (int i2 = 0; i2 < 16; ++i2) { float v = sval[gidx * 128 + s * 16 + i2]; ss += v * v; }
    ss += __shfl_xor(ss, 1); ss += __shfl_xor(ss, 2); ss += __shfl_xor(ss, 4);
    if (s == 0) snrm[gidx] = 1.0f / fmaxf(sqrtf(ss), 1e-12f);
  }
  __syncthreads();
  for (int i = 0; i < 16; ++i) {
    int c = i * 256 + tid;
    qkn[(size_t)bt * 4096 + c] = f2h(sval[c] * snrm[c >> 7]);
  }
}

// ---------------- chunked gated-linear-attention scan, single-fp16 MFMA, fp16 out ----------------
// grid 256 = dq(4) x h(32) x b(2); block 512 (8 waves); ~71 KB LDS.
__global__ __launch_bounds__(512, 4) void k_scanc(const u16* __restrict__ qk16, const u16* __restrict__ v16,
                                                  const float* __restrict__ cw,
                                                  const float* __restrict__ beta_t, const float* __restrict__ g_t,
                                                  u16* __restrict__ outr) {
  __shared__ __align__(16) u16 Qs[64][136], Ks[64][136];
  __shared__ __align__(16) u16 Vs[32][72];
  __shared__ __align__(16) u16 SIs[64][72];
  __shared__ __align__(16) u16 SH[2][32][132];
  __shared__ u16 rv16[67][36];
  __shared__ float garr[64], barr[64], warr[64], earr[64];
  __shared__ float sdt;

  const int tid = threadIdx.x;
  const int lane = tid & 63, wv = tid >> 6;
  const int l15 = lane & 15, l16 = lane >> 4;
  const int dq = blockIdx.x & 3, h = (blockIdx.x >> 2) & 31, b = blockIdx.x >> 7;
  const int bT = b * 2048;
  const int hk = h >> 1;
  const int dvl = tid & 31;
  const int vch = h * 128 + dq * 32;
  const float4 cwv = *(const float4*)&cw[(4096 + vch + dvl) * 4];
  const int mblk = wv & 3, nh = wv >> 2;
  const int m0 = mblk * 16;
  const int sr = tid >> 3, d0 = (tid & 7) * 16;
  const int r0v = tid >> 5;

  for (int i = tid; i < 2 * 32 * 132; i += 512) ((u16*)SH)[i] = 0;
  f32x4 st[2] = {};

  short8 pq[2], pk[2];
  u16 pv[5];
  auto LOADQK = [&](int t0) {
    const size_t base = (size_t)(bT + t0 + sr) * 4096 + hk * 128 + d0;
    pq[0] = *(const short8*)&qk16[base];        pq[1] = *(const short8*)&qk16[base + 8];
    pk[0] = *(const short8*)&qk16[base + 2048]; pk[1] = *(const short8*)&qk16[base + 2056];
  };
  auto LOADV = [&](int t0) {
#pragma unroll
    for (int i = 0; i < 5; ++i) {
      int r = r0v + i * 16;
      int tr = t0 - 3 + r;
      pv[i] = (r < 67 && tr >= 0) ? v16[(size_t)(bT + tr) * 4096 + vch + dvl] : (u16)0;
    }
  };

  LOADQK(0);
  LOADV(0);

  for (int ch = 0; ch < NCH; ++ch) {
    const int t0 = ch * CL;
    const int p = ch & 1;
    *(short8*)&Qs[sr][d0] = pq[0]; *(short8*)&Qs[sr][d0 + 8] = pq[1];
    *(short8*)&Ks[sr][d0] = pk[0]; *(short8*)&Ks[sr][d0 + 8] = pk[1];
#pragma unroll
    for (int i = 0; i < 5; ++i) {
      int r = r0v + i * 16;
      if (r < 67) rv16[r][dvl] = pv[i];
    }
    if (wv == 0) {
      float gv = g_t[h * 4096 + bT + t0 + lane];
      float bv = beta_t[h * 4096 + bT + t0 + lane];
      float cum = gv;
#pragma unroll
      for (int off = 1; off < 64; off <<= 1) {
        float o = __shfl_up(cum, off);
        if (lane >= off) cum += o;
      }
      float tot = __shfl(cum, 63);
      garr[lane] = cum;
      earr[lane] = __expf(cum);
      warr[lane] = __expf(tot - cum) * bv;
      barr[lane] = bv;
      if (lane == 0) sdt = __expf(tot);
    }
    __syncthreads();  // B1
    if (ch + 1 < NCH) {
      LOADQK(t0 + CL);
      LOADV(t0 + CL);
    }
    // ---- v conv + silu -> fp16 transposed [dv][s]
    {
      int tl = tid >> 5;
#pragma unroll
      for (int rr = 0; rr < 4; ++rr) {
        int t = rr * 16 + tl;
        float a = cwv.x * h2f(rv16[t][dvl]) + cwv.y * h2f(rv16[t + 1][dvl]) +
                  cwv.z * h2f(rv16[t + 2][dvl]) + cwv.w * h2f(rv16[t + 3][dvl]);
        a = a * sigm(a);
        Vs[dvl][t] = f2h(a);
      }
    }
    // ---- A = Q K^T; this wave: rows m0..m0+15, col blocks nh*2, nh*2+1
    half8 a[4];
#pragma unroll
    for (int kk = 0; kk < 4; ++kk) a[kk] = *(half8*)&Qs[m0 + l15][l16 * 8 + kk * 32];
#pragma unroll
    for (int j = 0; j < 2; ++j) {
      int n = nh * 2 + j;
      f32x4 a4 = {};
#pragma unroll
      for (int kk = 0; kk < 4; ++kk) {
        half8 b8 = *(half8*)&Ks[n * 16 + l15][l16 * 8 + kk * 32];
        a4 = __builtin_amdgcn_mfma_f32_16x16x32_f16(a[kk], b8, a4, 0, 0, 0);
      }
      int col = n * 16 + l15;
      float gc = garr[col], bc = barr[col];
#pragma unroll
      for (int i = 0; i < 4; ++i) {
        int row = m0 + l16 * 4 + i;
        float cval = (col <= row) ? __expf(garr[row] - gc) * bc * a4[i] : 0.f;
        SIs[row][col] = f2h(cval);
      }
    }
    __syncthreads();  // B2
    // ---- out_inter = Q @ St_prev, scaled by e^{Gc[t]}
    f32x4 ao = {};
#pragma unroll
    for (int kk = 0; kk < 4; ++kk) {
      half8 s8 = *(half8*)&SH[p][nh * 16 + l15][l16 * 8 + kk * 32];
      ao = __builtin_amdgcn_mfma_f32_16x16x32_f16(a[kk], s8, ao, 0, 0, 0);
    }
#pragma unroll
    for (int i = 0; i < 4; ++i) ao[i] *= earr[m0 + l16 * 4 + i];
    // ---- out += SI @ V
#pragma unroll
    for (int kk = 0; kk < 2; ++kk) {
      half8 asi = *(half8*)&SIs[m0 + l15][l16 * 8 + kk * 32];
      half8 bv8 = *(half8*)&Vs[nh * 16 + l15][l16 * 8 + kk * 32];
      ao = __builtin_amdgcn_mfma_f32_16x16x32_f16(asi, bv8, ao, 0, 0, 0);
    }
#pragma unroll
    for (int i = 0; i < 4; ++i)
      outr[(size_t)(bT + t0 + m0 + l16 * 4 + i) * 4096 + vch + nh * 16 + l15] = f2h(ao[i]);
    // ---- state update: St = sdt*St + V^T (K.w); this wave: dk band wv*16
#pragma unroll
    for (int m = 0; m < 2; ++m)
#pragma unroll
      for (int i = 0; i < 4; ++i) st[m][i] *= sdt;
#pragma unroll
    for (int kk = 0; kk < 2; ++kk) {
      half8 bw;
      {
        int dk = wv * 16 + l15;
#pragma unroll
        for (int e = 0; e < 8; ++e) {
          int s = l16 * 8 + e + kk * 32;
          bw[e] = (_Float16)(h2f(Ks[s][dk]) * warr[s]);
        }
      }
#pragma unroll
      for (int m = 0; m < 2; ++m) {
        half8 av = *(half8*)&Vs[m * 16 + l15][l16 * 8 + kk * 32];
        st[m] = __builtin_amdgcn_mfma_f32_16x16x32_f16(av, bw, st[m], 0, 0, 0);
      }
    }
#pragma unroll
    for (int m = 0; m < 2; ++m)
#pragma unroll
      for (int i = 0; i < 4; ++i)
        SH[p ^ 1][m * 16 + l16 * 4 + i][wv * 16 + l15] = f2h(st[m][i]);
    __syncthreads();  // B4
  }
}

// ---------------- per-(bt,head) RMS scale from fp16 outr ----------------
__global__ __launch_bounds__(256) void k_rms(const u16* __restrict__ outr, float* __restrict__ rms) {
  int pair = blockIdx.x * 4 + (threadIdx.x >> 6);
  int lane = threadIdx.x & 63;
  u32 pv = *(const u32*)&outr[(size_t)pair * 128 + lane * 2];
  float v0 = h2f((u16)pv), v1 = h2f((u16)(pv >> 16));
  float ss = v0 * v0 + v1 * v1;
#pragma unroll
  for (int m = 1; m < 64; m <<= 1) ss += __shfl_xor(ss, m);
  if (lane == 0) rms[pair] = rsqrtf(ss * (1.0f / 128.0f) + 1e-6f);
}

extern "C" void kernel_launch(void* const* d_in, const int* in_sizes, int n_in,
                              void* d_out, int out_size, void* d_ws, size_t ws_size,
                              hipStream_t stream) {
  const float* x = (const float*)d_in[0];
  // d_in[1] = positions (int64) — unused by the math
  const float* W_qkv = (const float*)d_in[2];
  const float* W_z = (const float*)d_in[3];
  const float* W_b = (const float*)d_in[4];
  const float* W_a = (const float*)d_in[5];
  const float* conv_w = (const float*)d_in[6];
  const float* dt_bias = (const float*)d_in[7];
  const float* A_log = (const float*)d_in[8];
  const float* norm_w = (const float*)d_in[9];
  const float* W_out = (const float*)d_in[10];
  float* out = (float*)d_out;

  const size_t MB = 1ull << 20;
  const size_t need = 192 * MB + 3 * (size_t)NBT * 32 * 4;  // == proven bound
  if (ws_size < need) {
    k_sentinel<<<1, 1, 0, stream>>>(out);
    return;
  }
  char* ws = (char*)d_ws;
  // [0,16)  xh (bf16 hi, ba GEMM)            — dead after ba GEMM
  // [16,32) xl (bf16 lo, ba GEMM)            — dead after ba GEMM
  // [32,48) xh16 (fp16 x; qk/v/z GEMMs)      — live through z GEMM
  // [48,64) wz16 (fp16 W_z, converted early) — live through z GEMM
  // [64,96) qkB16 (conv'd qk)                — dead after scan; then wout16
  // [96,128) qkA16 (raw qk)                  — dead after conv; then om16
  // [128,160) wsh16 (fp16 W_qkv, 8192 rows)  — dead after v GEMM; then outr16 (fp16)
  // [160,192) v16 (raw v)                    — dead after scan; early: wba/babuf
  u16* xh = (u16*)ws;
  u16* xl = (u16*)(ws + 16 * MB);
  u16* xh16 = (u16*)(ws + 32 * MB);
  u16* wz16 = (u16*)(ws + 48 * MB);
  u16* qkB16 = (u16*)(ws + 64 * MB);
  u16* wout16 = (u16*)(ws + 64 * MB);
  u16* qkA16 = (u16*)(ws + 96 * MB);
  u16* om16 = (u16*)(ws + 96 * MB);
  u16* wsh16 = (u16*)(ws + 128 * MB);
  u16* outr16 = (u16*)(ws + 128 * MB);
  u16* v16 = (u16*)(ws + 160 * MB);
  u16* wbah = (u16*)(ws + 160 * MB);
  u16* wbal = (u16*)(ws + 160 * MB + 512 * 1024);
  float* babuf = (float*)(ws + 161 * MB);
  float* beta_t = (float*)(ws + 192 * MB);
  float* g_t = beta_t + (size_t)NBT * 32;
  float* rmsb = g_t + (size_t)NBT * 32;

  const int N4X = NBT * NC / 4;
  // --- conversions + ba path ---
  k_cvtx<<<N4X / 256, 256, 0, stream>>>(x, xh, xl, xh16, N4X);
  k_cvt16<<<2 * N4X / 256, 256, 0, stream>>>(W_qkv, wsh16, 2 * N4X);  // full 8192 rows
  k_cvt16<<<N4X / 256, 256, 0, stream>>>(W_z, wz16, N4X);
  k_wba<<<128 * NC / 256, 256, 0, stream>>>(W_b, W_a, wbah, wbal);
  k_gemm_bf3<<<dim3(1, NBT / 128), 256, 0, stream>>>(xh, xl, wbah, wbal, babuf, NBT, 128, NC);
  k_bg<<<NBT * 32 / 256, 256, 0, stream>>>(babuf, dt_bias, A_log, beta_t, g_t);

  // --- qk projection (fp16, gload_lds dbuf) -> conv+norm -> qkB16 ---
  k_gemm16<1><<<dim3(4096 / 128, NBT / 128), 256, 0, stream>>>(xh16, wsh16, qkA16, NBT, 4096, NC,
                                                               nullptr, nullptr, nullptr);
  k_convqk<<<NBT, 256, 0, stream>>>(qkA16, conv_w, qkB16);

  // --- v projection (fp16, gload_lds dbuf) ---
  k_gemm16<1><<<dim3(4096 / 128, NBT / 128), 256, 0, stream>>>(xh16, wsh16 + (size_t)4096 * NC, v16,
                                                               NBT, 4096, NC, nullptr, nullptr, nullptr);

  // --- chunked scan -> outr16 (overlays wsh16, dead) ---
  k_scanc<<<256, 512, 0, stream>>>(qkB16, v16, conv_w, beta_t, g_t, outr16);
  k_rms<<<NBT * NHV / 4, 256, 0, stream>>>(outr16, rmsb);

  // --- z projection with fused gate epilogue -> om16 (overlays qkA16, dead) ---
  k_gemm16<2><<<dim3(VALD / 128, NBT / 128), 256, 0, stream>>>(xh16, wz16, om16, NBT, VALD, NC,
                                                               outr16, rmsb, norm_w);

  // --- output projection -> f32 out (wout16 overlays qkB16, dead after scan) ---
  k_cvt16<<<N4X / 256, 256, 0, stream>>>(W_out, wout16, N4X);
  k_gemm16<0><<<dim3(NC / 128, NBT / 128), 256, 0, stream>>>(om16, wout16, out, NBT, NC, VALD,
                                                             nullptr, nullptr, nullptr);
}

// Round 20
// 644.232 us; speedup vs baseline: 1.3130x; 1.0207x over previous
//
#include <hip/hip_runtime.h>

typedef unsigned short u16;
typedef unsigned int u32;
typedef __attribute__((ext_vector_type(8))) short short8;
typedef __attribute__((ext_vector_type(8))) _Float16 half8;
typedef __attribute__((ext_vector_type(4))) float f32x4;

#define NB 2
#define NT 2048
#define NC 2048
#define NHV 32
#define VALD 4096
#define NBT 4096
#define CL 64
#define NCH (NT / CL)

#define GL16(gp, lp) __builtin_amdgcn_global_load_lds( \
    (const __attribute__((address_space(1))) unsigned int*)(gp), \
    (__attribute__((address_space(3))) unsigned int*)(lp), 16, 0, 0)

static __device__ __forceinline__ float bf2f(u16 u) {
  union { u32 u; float f; } x; x.u = ((u32)u) << 16; return x.f;
}
static __device__ __forceinline__ u16 f2bf(float f) {
  union { float f; u32 u; } x; x.f = f;
  u32 r = x.u + 0x7fffu + ((x.u >> 16) & 1u);
  return (u16)(r >> 16);
}
static __device__ __forceinline__ u16 f2h(float f) {
  union { _Float16 h; u16 u; } c; c.h = (_Float16)f; return c.u;
}
static __device__ __forceinline__ float h2f(u16 u) {
  union { u16 u; _Float16 h; } c; c.u = u; return (float)c.h;
}
static __device__ __forceinline__ float sigm(float x) { return 1.0f / (1.0f + __expf(-x)); }
static __device__ __forceinline__ int ldsoff(int row, int c8) {
  return row * 48 + ((c8 ^ ((row >> 2) & 3)) << 3);
}

// ---------------- sentinel ----------------
__global__ void k_sentinel(float* out) { out[0] = 1.0e6f; }

// ---------------- x -> bf16 hi/lo planes + fp16 plane (single read of x) ----------------
__global__ __launch_bounds__(256) void k_cvtx(const float* __restrict__ in, u16* __restrict__ hi,
                                              u16* __restrict__ lo, u16* __restrict__ h16, int n4) {
  int i = blockIdx.x * 256 + threadIdx.x;
  if (i >= n4) return;
  float4 v = ((const float4*)in)[i];
  ushort4 h, l, p;
  h.x = f2bf(v.x); l.x = f2bf(v.x - bf2f(h.x)); p.x = f2h(v.x);
  h.y = f2bf(v.y); l.y = f2bf(v.y - bf2f(h.y)); p.y = f2h(v.y);
  h.z = f2bf(v.z); l.z = f2bf(v.z - bf2f(h.z)); p.z = f2h(v.z);
  h.w = f2bf(v.w); l.w = f2bf(v.w - bf2f(h.w)); p.w = f2h(v.w);
  ((ushort4*)hi)[i] = h;
  ((ushort4*)lo)[i] = l;
  ((ushort4*)h16)[i] = p;
}

// ---------------- f32 -> fp16 plane ----------------
__global__ __launch_bounds__(256) void k_cvt16(const float* __restrict__ in, u16* __restrict__ out, int n4) {
  int i = blockIdx.x * 256 + threadIdx.x;
  if (i >= n4) return;
  float4 v = ((const float4*)in)[i];
  ushort4 o;
  o.x = f2h(v.x); o.y = f2h(v.y); o.z = f2h(v.z); o.w = f2h(v.w);
  ((ushort4*)out)[i] = o;
}

// ---------------- build padded W_ba hi/lo bf16 planes [128][2048] ----------------
__global__ __launch_bounds__(256) void k_wba(const float* __restrict__ Wb, const float* __restrict__ Wa,
                                             u16* __restrict__ hi, u16* __restrict__ lo) {
  int i = blockIdx.x * 256 + threadIdx.x;
  int r = i >> 11, c = i & 2047;
  float v = 0.f;
  if (r < 32) v = Wb[r * 2048 + c];
  else if (r < 64) v = Wa[(r - 32) * 2048 + c];
  u16 h = f2bf(v);
  hi[i] = h;
  lo[i] = f2bf(v - bf2f(h));
}

// ---------------- 3-pass bf16 GEMM (ba projection; recurrence-gate path) ----------------
__global__ __launch_bounds__(256) void k_gemm_bf3(const u16* __restrict__ Ahg, const u16* __restrict__ Alg,
                                                  const u16* __restrict__ Bhg, const u16* __restrict__ Blg,
                                                  float* __restrict__ C0, int M, int N, int K) {
  __shared__ __align__(16) u16 As_h[128 * 48];
  __shared__ __align__(16) u16 As_l[128 * 48];
  __shared__ __align__(16) u16 Bs_h[128 * 48];
  __shared__ __align__(16) u16 Bs_l[128 * 48];
  const int tid = threadIdx.x;
  const int lane = tid & 63, wave = tid >> 6;
  const int wr = wave >> 1, wc = wave & 1;
  const int l15 = lane & 15, l16 = lane >> 4;
  const int row0 = blockIdx.y * 128, col0 = blockIdx.x * 128;
  const int sr = tid >> 1, sk = (tid & 1) * 16;
  const int c0 = sk >> 3;
  const int w0 = ldsoff(sr, c0), w1 = ldsoff(sr, c0 + 1);
  f32x4 acc[4][4] = {};
  for (int k0 = 0; k0 < K; k0 += 32) {
    const size_t aoff = (size_t)(row0 + sr) * K + k0 + sk;
    const size_t boff = (size_t)(col0 + sr) * K + k0 + sk;
    *(short8*)&As_h[w0] = *(const short8*)&Ahg[aoff];
    *(short8*)&As_h[w1] = *(const short8*)&Ahg[aoff + 8];
    *(short8*)&As_l[w0] = *(const short8*)&Alg[aoff];
    *(short8*)&As_l[w1] = *(const short8*)&Alg[aoff + 8];
    *(short8*)&Bs_h[w0] = *(const short8*)&Bhg[boff];
    *(short8*)&Bs_h[w1] = *(const short8*)&Bhg[boff + 8];
    *(short8*)&Bs_l[w0] = *(const short8*)&Blg[boff];
    *(short8*)&Bs_l[w1] = *(const short8*)&Blg[boff + 8];
    __syncthreads();
    short8 ah[4], al[4], bh[4], bl[4];
#pragma unroll
    for (int mi = 0; mi < 4; ++mi) {
      int off = ldsoff(wr * 64 + mi * 16 + l15, l16);
      ah[mi] = *(short8*)&As_h[off];
      al[mi] = *(short8*)&As_l[off];
    }
#pragma unroll
    for (int ni = 0; ni < 4; ++ni) {
      int off = ldsoff(wc * 64 + ni * 16 + l15, l16);
      bh[ni] = *(short8*)&Bs_h[off];
      bl[ni] = *(short8*)&Bs_l[off];
    }
#pragma unroll
    for (int mi = 0; mi < 4; ++mi)
#pragma unroll
      for (int ni = 0; ni < 4; ++ni) {
        acc[mi][ni] = __builtin_amdgcn_mfma_f32_16x16x32_bf16(ah[mi], bh[ni], acc[mi][ni], 0, 0, 0);
        acc[mi][ni] = __builtin_amdgcn_mfma_f32_16x16x32_bf16(al[mi], bh[ni], acc[mi][ni], 0, 0, 0);
        acc[mi][ni] = __builtin_amdgcn_mfma_f32_16x16x32_bf16(ah[mi], bl[ni], acc[mi][ni], 0, 0, 0);
      }
    __syncthreads();
  }
#pragma unroll
  for (int mi = 0; mi < 4; ++mi)
#pragma unroll
    for (int ni = 0; ni < 4; ++ni) {
      int rr = row0 + wr * 64 + mi * 16 + l16 * 4;
      int cc = col0 + wc * 64 + ni * 16 + l15;
#pragma unroll
      for (int i = 0; i < 4; ++i)
        C0[(size_t)(rr + i) * N + cc] = acc[mi][ni][i];
    }
}

// ---------------- single-pass fp16 GEMM, 128x128 tile, BK=64, gload_lds dbuf, XCD swizzle --------
// 1D grid (nblocks % 8 == 0). One barrier per K-tile: sync -> prefetch(t+1) -> MFMA(t).
// MODE 0: f32 out. MODE 1: fp16 out. MODE 2: z epilogue (e0 fp16) -> fp16 out.
template <int MODE>
__global__ __launch_bounds__(256) void k_gemm16(const u16* __restrict__ Ag, const u16* __restrict__ Bg,
                                                void* __restrict__ C0, int M, int N, int K,
                                                const u16* __restrict__ e0, const float* __restrict__ e1,
                                                const float* __restrict__ e2) {
  __shared__ __align__(16) u16 As[2 * 128 * 64];
  __shared__ __align__(16) u16 Bs[2 * 128 * 64];
  const int tid = threadIdx.x;
  const int lane = tid & 63, wave = tid >> 6;
  const int wr = wave >> 1, wc = wave & 1;
  const int l15 = lane & 15, l16 = lane >> 4;
  // bijective XCD swizzle
  const int qx = gridDim.x >> 3;
  const int swz = ((int)blockIdx.x & 7) * qx + ((int)blockIdx.x >> 3);
  const int nbx = N >> 7;
  const int row0 = (swz / nbx) * 128, col0 = (swz % nbx) * 128;
  // staging maps: per matrix 4 gload_lds per wave; instr i covers rows wave*32+i*8 .. +8
  u32 gA[4], gB[4], lofs[4];
#pragma unroll
  for (int i = 0; i < 4; ++i) {
    int o = wave * 2048 + i * 512 + lane * 8;        // element offset (linear LDS)
    int row = o >> 6;
    int cg = ((lane & 7) ^ (row & 7)) * 8;           // pre-swizzled global k-chunk
    gA[i] = (u32)(row0 + row) * (u32)K + cg;
    gB[i] = (u32)(col0 + row) * (u32)K + cg;
    lofs[i] = (u32)(wave * 2048 + i * 512);          // wave-uniform LDS base
  }
  f32x4 acc[4][4] = {};
  const int NTILE = K >> 6;
  // prologue: stage tile 0 into buf 0
#pragma unroll
  for (int i = 0; i < 4; ++i) {
    GL16(Ag + gA[i], &As[lofs[i]]);
    GL16(Bg + gB[i], &Bs[lofs[i]]);
  }
  for (int t = 0; t < NTILE; ++t) {
    const u32 cb = (u32)(t & 1) * 8192;
    __syncthreads();  // drains vmcnt (tile t staged) + lgkm (prev reads done)
    if (t + 1 < NTILE) {
      const u32 nb = cb ^ 8192;
      const int kn = (t + 1) << 6;
#pragma unroll
      for (int i = 0; i < 4; ++i) {
        GL16(Ag + gA[i] + kn, &As[nb + lofs[i]]);
        GL16(Bg + gB[i] + kn, &Bs[nb + lofs[i]]);
      }
    }
#pragma unroll
    for (int kk = 0; kk < 2; ++kk) {
      half8 a[4], b[4];
#pragma unroll
      for (int mi = 0; mi < 4; ++mi) {
        int row = wr * 64 + mi * 16 + l15;
        a[mi] = *(half8*)&As[cb + row * 64 + (((kk * 4 + l16) ^ (l15 & 7)) << 3)];
      }
#pragma unroll
      for (int ni = 0; ni < 4; ++ni) {
        int row = wc * 64 + ni * 16 + l15;
        b[ni] = *(half8*)&Bs[cb + row * 64 + (((kk * 4 + l16) ^ (l15 & 7)) << 3)];
      }
#pragma unroll
      for (int mi = 0; mi < 4; ++mi)
#pragma unroll
        for (int ni = 0; ni < 4; ++ni)
          acc[mi][ni] = __builtin_amdgcn_mfma_f32_16x16x32_f16(a[mi], b[ni], acc[mi][ni], 0, 0, 0);
    }
  }
#pragma unroll
  for (int mi = 0; mi < 4; ++mi) {
#pragma unroll
    for (int ni = 0; ni < 4; ++ni) {
      int rr = row0 + wr * 64 + mi * 16 + l16 * 4;
      int cc = col0 + wc * 64 + ni * 16 + l15;
#pragma unroll
      for (int i = 0; i < 4; ++i) {
        float v = acc[mi][ni][i];
        size_t idx = (size_t)(rr + i) * N + cc;
        if constexpr (MODE == 0) {
          ((float*)C0)[idx] = v;
        } else if constexpr (MODE == 1) {
          ((u16*)C0)[idx] = f2h(v);
        } else {
          float zs = v * sigm(v);
          float o = h2f(e0[idx]) * e1[(size_t)(rr + i) * 32 + (cc >> 7)] * e2[cc & 127] * zs;
          ((u16*)C0)[idx] = f2h(o);
        }
      }
    }
  }
}

// ---------------- beta / g from ba [BT,128] f32, TRANSPOSED out [32][4096] ----------------
__global__ __launch_bounds__(256) void k_bg(const float* __restrict__ ba, const float* __restrict__ dt_bias,
                                            const float* __restrict__ A_log, float* __restrict__ beta_t,
                                            float* __restrict__ g_t) {
  int i = blockIdx.x * 256 + threadIdx.x;
  int bt = i >> 5, h = i & 31;
  float bv = ba[(size_t)bt * 128 + h];
  float av = ba[(size_t)bt * 128 + 32 + h];
  beta_t[h * 4096 + bt] = sigm(bv);
  float xx = av + dt_bias[h];
  float sp = (xx > 20.f) ? xx : log1pf(__expf(xx));
  g_t[h * 4096 + bt] = -__expf(A_log[h]) * sp;
}

// ---------------- conv+SiLU+L2norm for q,k: fp16 in [4096][4096] -> fp16 out ----------------
__global__ __launch_bounds__(256) void k_convqk(const u16* __restrict__ qkraw, const float* __restrict__ cw,
                                                u16* __restrict__ qkn) {
  __shared__ float sval[4096];
  __shared__ float snrm[32];
  const int tid = threadIdx.x;
  const int bt = blockIdx.x;
  const int b = bt >> 11, t = bt & 2047;
  for (int i = 0; i < 16; ++i) {
    int c = i * 256 + tid;
    float acc = 0.f;
#pragma unroll
    for (int j = 0; j < 4; ++j) {
      int ts = t - 3 + j;
      if (ts >= 0) acc += cw[c * 4 + j] * h2f(qkraw[(size_t)(b * 2048 + ts) * 4096 + c]);
    }
    sval[c] = acc * sigm(acc);
  }
  __syncthreads();
  {
    int gidx = tid >> 3, s = tid & 7;
    float ss = 0.f;
#pragma unroll
    for (int i2 = 0; i2 < 16; ++i2) { float v = sval[gidx * 128 + s * 16 + i2]; ss += v * v; }
    ss += __shfl_xor(ss, 1); ss += __shfl_xor(ss, 2); ss += __shfl_xor(ss, 4);
    if (s == 0) snrm[gidx] = 1.0f / fmaxf(sqrtf(ss), 1e-12f);
  }
  __syncthreads();
  for (int i = 0; i < 16; ++i) {
    int c = i * 256 + tid;
    qkn[(size_t)bt * 4096 + c] = f2h(sval[c] * snrm[c >> 7]);
  }
}

// ---------------- chunked gated-linear-attention scan, single-fp16 MFMA, fp16 out ----------------
// grid 256 = dq(4) x h(32) x b(2); block 512 (8 waves); ~72 KB LDS.
// Gate pipeline: cumsum for chunk ch+1 computed by wave 0 during chunk ch (double-buffered).
__global__ __launch_bounds__(512, 4) void k_scanc(const u16* __restrict__ qk16, const u16* __restrict__ v16,
                                                  const float* __restrict__ cw,
                                                  const float* __restrict__ beta_t, const float* __restrict__ g_t,
                                                  u16* __restrict__ outr) {
  __shared__ __align__(16) u16 Qs[64][136], Ks[64][136];
  __shared__ __align__(16) u16 Vs[32][72];
  __shared__ __align__(16) u16 SIs[64][72];
  __shared__ __align__(16) u16 SH[2][32][132];
  __shared__ u16 rv16[67][36];
  __shared__ float garr[2][64], barr[2][64], warr[2][64], earr[2][64];
  __shared__ float sdt[2];

  const int tid = threadIdx.x;
  const int lane = tid & 63, wv = tid >> 6;
  const int l15 = lane & 15, l16 = lane >> 4;
  const int dq = blockIdx.x & 3, h = (blockIdx.x >> 2) & 31, b = blockIdx.x >> 7;
  const int bT = b * 2048;
  const int hk = h >> 1;
  const int dvl = tid & 31;
  const int vch = h * 128 + dq * 32;
  const float4 cwv = *(const float4*)&cw[(4096 + vch + dvl) * 4];
  const int mblk = wv & 3, nh = wv >> 2;
  const int m0 = mblk * 16;
  const int sr = tid >> 3, d0 = (tid & 7) * 16;
  const int r0v = tid >> 5;

  for (int i = tid; i < 2 * 32 * 132; i += 512) ((u16*)SH)[i] = 0;
  f32x4 st[2] = {};

  short8 pq[2], pk[2];
  u16 pv[5];
  float pgv, pbv;
  auto LOADQK = [&](int t0) {
    const size_t base = (size_t)(bT + t0 + sr) * 4096 + hk * 128 + d0;
    pq[0] = *(const short8*)&qk16[base];        pq[1] = *(const short8*)&qk16[base + 8];
    pk[0] = *(const short8*)&qk16[base + 2048]; pk[1] = *(const short8*)&qk16[base + 2056];
  };
  auto LOADV = [&](int t0) {
#pragma unroll
    for (int i = 0; i < 5; ++i) {
      int r = r0v + i * 16;
      int tr = t0 - 3 + r;
      pv[i] = (r < 67 && tr >= 0) ? v16[(size_t)(bT + tr) * 4096 + vch + dvl] : (u16)0;
    }
  };
  auto CUMSUM = [&](float gv, float bv, int buf) {
    float cum = gv;
#pragma unroll
    for (int off = 1; off < 64; off <<= 1) {
      float o = __shfl_up(cum, off);
      if (lane >= off) cum += o;
    }
    float tot = __shfl(cum, 63);
    garr[buf][lane] = cum;
    earr[buf][lane] = __expf(cum);
    warr[buf][lane] = __expf(tot - cum) * bv;
    barr[buf][lane] = bv;
    if (lane == 0) sdt[buf] = __expf(tot);
  };

  LOADQK(0);
  LOADV(0);
  if (wv == 0) {
    float gv = g_t[h * 4096 + bT + lane];
    float bv = beta_t[h * 4096 + bT + lane];
    CUMSUM(gv, bv, 0);
  }

  for (int ch = 0; ch < NCH; ++ch) {
    const int t0 = ch * CL;
    const int p = ch & 1;
    *(short8*)&Qs[sr][d0] = pq[0]; *(short8*)&Qs[sr][d0 + 8] = pq[1];
    *(short8*)&Ks[sr][d0] = pk[0]; *(short8*)&Ks[sr][d0 + 8] = pk[1];
#pragma unroll
    for (int i = 0; i < 5; ++i) {
      int r = r0v + i * 16;
      if (r < 67) rv16[r][dvl] = pv[i];
    }
    __syncthreads();  // B1 (orders Qs/Ks/rv writes; garr[p] written >=1 barrier ago)
    if (ch + 1 < NCH) {
      LOADQK(t0 + CL);
      LOADV(t0 + CL);
      if (wv == 0) {
        pgv = g_t[h * 4096 + bT + t0 + CL + lane];
        pbv = beta_t[h * 4096 + bT + t0 + CL + lane];
      }
    }
    // ---- v conv + silu -> fp16 transposed [dv][s]
    {
      int tl = tid >> 5;
#pragma unroll
      for (int rr = 0; rr < 4; ++rr) {
        int t = rr * 16 + tl;
        float a = cwv.x * h2f(rv16[t][dvl]) + cwv.y * h2f(rv16[t + 1][dvl]) +
                  cwv.z * h2f(rv16[t + 2][dvl]) + cwv.w * h2f(rv16[t + 3][dvl]);
        a = a * sigm(a);
        Vs[dvl][t] = f2h(a);
      }
    }
    // ---- A = Q K^T; this wave: rows m0..m0+15, col blocks nh*2, nh*2+1
    half8 a[4];
#pragma unroll
    for (int kk = 0; kk < 4; ++kk) a[kk] = *(half8*)&Qs[m0 + l15][l16 * 8 + kk * 32];
#pragma unroll
    for (int j = 0; j < 2; ++j) {
      int n = nh * 2 + j;
      f32x4 a4 = {};
#pragma unroll
      for (int kk = 0; kk < 4; ++kk) {
        half8 b8 = *(half8*)&Ks[n * 16 + l15][l16 * 8 + kk * 32];
        a4 = __builtin_amdgcn_mfma_f32_16x16x32_f16(a[kk], b8, a4, 0, 0, 0);
      }
      int col = n * 16 + l15;
      float gc = garr[p][col], bc = barr[p][col];
#pragma unroll
      for (int i = 0; i < 4; ++i) {
        int row = m0 + l16 * 4 + i;
        float cval = (col <= row) ? __expf(garr[p][row] - gc) * bc * a4[i] : 0.f;
        SIs[row][col] = f2h(cval);
      }
    }
    __syncthreads();  // B2
    // ---- out_inter = Q @ St_prev, scaled by e^{Gc[t]}
    f32x4 ao = {};
#pragma unroll
    for (int kk = 0; kk < 4; ++kk) {
      half8 s8 = *(half8*)&SH[p][nh * 16 + l15][l16 * 8 + kk * 32];
      ao = __builtin_amdgcn_mfma_f32_16x16x32_f16(a[kk], s8, ao, 0, 0, 0);
    }
#pragma unroll
    for (int i = 0; i < 4; ++i) ao[i] *= earr[p][m0 + l16 * 4 + i];
    // ---- out += SI @ V
#pragma unroll
    for (int kk = 0; kk < 2; ++kk) {
      half8 asi = *(half8*)&SIs[m0 + l15][l16 * 8 + kk * 32];
      half8 bv8 = *(half8*)&Vs[nh * 16 + l15][l16 * 8 + kk * 32];
      ao = __builtin_amdgcn_mfma_f32_16x16x32_f16(asi, bv8, ao, 0, 0, 0);
    }
#pragma unroll
    for (int i = 0; i < 4; ++i)
      outr[(size_t)(bT + t0 + m0 + l16 * 4 + i) * 4096 + vch + nh * 16 + l15] = f2h(ao[i]);
    // ---- state update: St = sdt*St + V^T (K.w); this wave: dk band wv*16
    const float sd = sdt[p];
#pragma unroll
    for (int m = 0; m < 2; ++m)
#pragma unroll
      for (int i = 0; i < 4; ++i) st[m][i] *= sd;
#pragma unroll
    for (int kk = 0; kk < 2; ++kk) {
      half8 bw;
      {
        int dk = wv * 16 + l15;
#pragma unroll
        for (int e = 0; e < 8; ++e) {
          int s = l16 * 8 + e + kk * 32;
          bw[e] = (_Float16)(h2f(Ks[s][dk]) * warr[p][s]);
        }
      }
#pragma unroll
      for (int m = 0; m < 2; ++m) {
        half8 av = *(half8*)&Vs[m * 16 + l15][l16 * 8 + kk * 32];
        st[m] = __builtin_amdgcn_mfma_f32_16x16x32_f16(av, bw, st[m], 0, 0, 0);
      }
    }
#pragma unroll
    for (int m = 0; m < 2; ++m)
#pragma unroll
      for (int i = 0; i < 4; ++i)
        SH[p ^ 1][m * 16 + l16 * 4 + i][wv * 16 + l15] = f2h(st[m][i]);
    // ---- gate pipeline: wave 0 prepares chunk ch+1's cumsum (overlaps other waves' phase 4)
    if (wv == 0 && ch + 1 < NCH) CUMSUM(pgv, pbv, p ^ 1);
    __syncthreads();  // B4
  }
}

// ---------------- per-(bt,head) RMS scale from fp16 outr ----------------
__global__ __launch_bounds__(256) void k_rms(const u16* __restrict__ outr, float* __restrict__ rms) {
  int pair = blockIdx.x * 4 + (threadIdx.x >> 6);
  int lane = threadIdx.x & 63;
  u32 pv = *(const u32*)&outr[(size_t)pair * 128 + lane * 2];
  float v0 = h2f((u16)pv), v1 = h2f((u16)(pv >> 16));
  float ss = v0 * v0 + v1 * v1;
#pragma unroll
  for (int m = 1; m < 64; m <<= 1) ss += __shfl_xor(ss, m);
  if (lane == 0) rms[pair] = rsqrtf(ss * (1.0f / 128.0f) + 1e-6f);
}

extern "C" void kernel_launch(void* const* d_in, const int* in_sizes, int n_in,
                              void* d_out, int out_size, void* d_ws, size_t ws_size,
                              hipStream_t stream) {
  const float* x = (const float*)d_in[0];
  // d_in[1] = positions (int64) — unused by the math
  const float* W_qkv = (const float*)d_in[2];
  const float* W_z = (const float*)d_in[3];
  const float* W_b = (const float*)d_in[4];
  const float* W_a = (const float*)d_in[5];
  const float* conv_w = (const float*)d_in[6];
  const float* dt_bias = (const float*)d_in[7];
  const float* A_log = (const float*)d_in[8];
  const float* norm_w = (const float*)d_in[9];
  const float* W_out = (const float*)d_in[10];
  float* out = (float*)d_out;

  const size_t MB = 1ull << 20;
  const size_t need = 192 * MB + 3 * (size_t)NBT * 32 * 4;  // == proven bound
  if (ws_size < need) {
    k_sentinel<<<1, 1, 0, stream>>>(out);
    return;
  }
  char* ws = (char*)d_ws;
  u16* xh = (u16*)ws;
  u16* xl = (u16*)(ws + 16 * MB);
  u16* xh16 = (u16*)(ws + 32 * MB);
  u16* wz16 = (u16*)(ws + 48 * MB);
  u16* qkB16 = (u16*)(ws + 64 * MB);
  u16* wout16 = (u16*)(ws + 64 * MB);
  u16* qkA16 = (u16*)(ws + 96 * MB);
  u16* om16 = (u16*)(ws + 96 * MB);
  u16* wsh16 = (u16*)(ws + 128 * MB);
  u16* outr16 = (u16*)(ws + 128 * MB);
  u16* v16 = (u16*)(ws + 160 * MB);
  u16* wbah = (u16*)(ws + 160 * MB);
  u16* wbal = (u16*)(ws + 160 * MB + 512 * 1024);
  float* babuf = (float*)(ws + 161 * MB);
  float* beta_t = (float*)(ws + 192 * MB);
  float* g_t = beta_t + (size_t)NBT * 32;
  float* rmsb = g_t + (size_t)NBT * 32;

  const int N4X = NBT * NC / 4;
  // --- conversions + ba path ---
  k_cvtx<<<N4X / 256, 256, 0, stream>>>(x, xh, xl, xh16, N4X);
  k_cvt16<<<2 * N4X / 256, 256, 0, stream>>>(W_qkv, wsh16, 2 * N4X);  // full 8192 rows
  k_cvt16<<<N4X / 256, 256, 0, stream>>>(W_z, wz16, N4X);
  k_wba<<<128 * NC / 256, 256, 0, stream>>>(W_b, W_a, wbah, wbal);
  k_gemm_bf3<<<dim3(1, NBT / 128), 256, 0, stream>>>(xh, xl, wbah, wbal, babuf, NBT, 128, NC);
  k_bg<<<NBT * 32 / 256, 256, 0, stream>>>(babuf, dt_bias, A_log, beta_t, g_t);

  // --- qk projection (fp16, gload_lds dbuf, XCD swizzle) -> conv+norm -> qkB16 ---
  k_gemm16<1><<<(NBT / 128) * (4096 / 128), 256, 0, stream>>>(xh16, wsh16, qkA16, NBT, 4096, NC,
                                                              nullptr, nullptr, nullptr);
  k_convqk<<<NBT, 256, 0, stream>>>(qkA16, conv_w, qkB16);

  // --- v projection ---
  k_gemm16<1><<<(NBT / 128) * (4096 / 128), 256, 0, stream>>>(xh16, wsh16 + (size_t)4096 * NC, v16,
                                                              NBT, 4096, NC, nullptr, nullptr, nullptr);

  // --- chunked scan -> outr16 (overlays wsh16, dead) ---
  k_scanc<<<256, 512, 0, stream>>>(qkB16, v16, conv_w, beta_t, g_t, outr16);
  k_rms<<<NBT * NHV / 4, 256, 0, stream>>>(outr16, rmsb);

  // --- z projection with fused gate epilogue -> om16 (overlays qkA16, dead) ---
  k_gemm16<2><<<(NBT / 128) * (VALD / 128), 256, 0, stream>>>(xh16, wz16, om16, NBT, VALD, NC,
                                                              outr16, rmsb, norm_w);

  // --- output projection -> f32 out (wout16 overlays qkB16, dead after scan) ---
  k_cvt16<<<N4X / 256, 256, 0, stream>>>(W_out, wout16, N4X);
  k_gemm16<0><<<(NBT / 128) * (NC / 128), 256, 0, stream>>>(om16, wout16, out, NBT, NC, VALD,
                                                            nullptr, nullptr, nullptr);
}

// Round 21
// 588.903 us; speedup vs baseline: 1.4363x; 1.0940x over previous
//
#include <hip/hip_runtime.h>

typedef unsigned short u16;
typedef unsigned int u32;
typedef __attribute__((ext_vector_type(8))) short short8;
typedef __attribute__((ext_vector_type(8))) _Float16 half8;
typedef __attribute__((ext_vector_type(4))) float f32x4;

#define NB 2
#define NT 2048
#define NC 2048
#define NHV 32
#define VALD 4096
#define NBT 4096
#define CL 64
#define NCH (NT / CL)

#define GL16(gp, lp) __builtin_amdgcn_global_load_lds( \
    (const __attribute__((address_space(1))) unsigned int*)(gp), \
    (__attribute__((address_space(3))) unsigned int*)(lp), 16, 0, 0)

static __device__ __forceinline__ float bf2f(u16 u) {
  union { u32 u; float f; } x; x.u = ((u32)u) << 16; return x.f;
}
static __device__ __forceinline__ u16 f2bf(float f) {
  union { float f; u32 u; } x; x.f = f;
  u32 r = x.u + 0x7fffu + ((x.u >> 16) & 1u);
  return (u16)(r >> 16);
}
static __device__ __forceinline__ u16 f2h(float f) {
  union { _Float16 h; u16 u; } c; c.h = (_Float16)f; return c.u;
}
static __device__ __forceinline__ float h2f(u16 u) {
  union { u16 u; _Float16 h; } c; c.u = u; return (float)c.h;
}
static __device__ __forceinline__ float sigm(float x) { return 1.0f / (1.0f + __expf(-x)); }
static __device__ __forceinline__ int ldsoff(int row, int c8) {
  return row * 48 + ((c8 ^ ((row >> 2) & 3)) << 3);
}

// ---------------- sentinel ----------------
__global__ void k_sentinel(float* out) { out[0] = 1.0e6f; }

// ---------------- x -> bf16 hi/lo planes + fp16 plane (single read of x) ----------------
__global__ __launch_bounds__(256) void k_cvtx(const float* __restrict__ in, u16* __restrict__ hi,
                                              u16* __restrict__ lo, u16* __restrict__ h16, int n4) {
  int i = blockIdx.x * 256 + threadIdx.x;
  if (i >= n4) return;
  float4 v = ((const float4*)in)[i];
  ushort4 h, l, p;
  h.x = f2bf(v.x); l.x = f2bf(v.x - bf2f(h.x)); p.x = f2h(v.x);
  h.y = f2bf(v.y); l.y = f2bf(v.y - bf2f(h.y)); p.y = f2h(v.y);
  h.z = f2bf(v.z); l.z = f2bf(v.z - bf2f(h.z)); p.z = f2h(v.z);
  h.w = f2bf(v.w); l.w = f2bf(v.w - bf2f(h.w)); p.w = f2h(v.w);
  ((ushort4*)hi)[i] = h;
  ((ushort4*)lo)[i] = l;
  ((ushort4*)h16)[i] = p;
}

// ---------------- f32 -> fp16 plane ----------------
__global__ __launch_bounds__(256) void k_cvt16(const float* __restrict__ in, u16* __restrict__ out, int n4) {
  int i = blockIdx.x * 256 + threadIdx.x;
  if (i >= n4) return;
  float4 v = ((const float4*)in)[i];
  ushort4 o;
  o.x = f2h(v.x); o.y = f2h(v.y); o.z = f2h(v.z); o.w = f2h(v.w);
  ((ushort4*)out)[i] = o;
}

// ---------------- build padded W_ba hi/lo bf16 planes [128][2048] ----------------
__global__ __launch_bounds__(256) void k_wba(const float* __restrict__ Wb, const float* __restrict__ Wa,
                                             u16* __restrict__ hi, u16* __restrict__ lo) {
  int i = blockIdx.x * 256 + threadIdx.x;
  int r = i >> 11, c = i & 2047;
  float v = 0.f;
  if (r < 32) v = Wb[r * 2048 + c];
  else if (r < 64) v = Wa[(r - 32) * 2048 + c];
  u16 h = f2bf(v);
  hi[i] = h;
  lo[i] = f2bf(v - bf2f(h));
}

// ---------------- 3-pass bf16 GEMM, split-K x4 (ba projection) ----------------
// grid (4, Mtiles): blockIdx.x = K-chunk (K/4 each); partial f32 out at C0 + kc*M*N.
__global__ __launch_bounds__(256) void k_gemm_bf3(const u16* __restrict__ Ahg, const u16* __restrict__ Alg,
                                                  const u16* __restrict__ Bhg, const u16* __restrict__ Blg,
                                                  float* __restrict__ C0, int M, int N, int K) {
  __shared__ __align__(16) u16 As_h[128 * 48];
  __shared__ __align__(16) u16 As_l[128 * 48];
  __shared__ __align__(16) u16 Bs_h[128 * 48];
  __shared__ __align__(16) u16 Bs_l[128 * 48];
  const int tid = threadIdx.x;
  const int lane = tid & 63, wave = tid >> 6;
  const int wr = wave >> 1, wc = wave & 1;
  const int l15 = lane & 15, l16 = lane >> 4;
  const int kc = blockIdx.x;
  const int Kc = K >> 2;
  const int kbase = kc * Kc;
  const int row0 = blockIdx.y * 128, col0 = 0;
  float* Cp = C0 + (size_t)kc * M * N;
  const int sr = tid >> 1, sk = (tid & 1) * 16;
  const int c0 = sk >> 3;
  const int w0 = ldsoff(sr, c0), w1 = ldsoff(sr, c0 + 1);
  f32x4 acc[4][4] = {};
  for (int k0 = kbase; k0 < kbase + Kc; k0 += 32) {
    const size_t aoff = (size_t)(row0 + sr) * K + k0 + sk;
    const size_t boff = (size_t)(col0 + sr) * K + k0 + sk;
    *(short8*)&As_h[w0] = *(const short8*)&Ahg[aoff];
    *(short8*)&As_h[w1] = *(const short8*)&Ahg[aoff + 8];
    *(short8*)&As_l[w0] = *(const short8*)&Alg[aoff];
    *(short8*)&As_l[w1] = *(const short8*)&Alg[aoff + 8];
    *(short8*)&Bs_h[w0] = *(const short8*)&Bhg[boff];
    *(short8*)&Bs_h[w1] = *(const short8*)&Bhg[boff + 8];
    *(short8*)&Bs_l[w0] = *(const short8*)&Blg[boff];
    *(short8*)&Bs_l[w1] = *(const short8*)&Blg[boff + 8];
    __syncthreads();
    short8 ah[4], al[4], bh[4], bl[4];
#pragma unroll
    for (int mi = 0; mi < 4; ++mi) {
      int off = ldsoff(wr * 64 + mi * 16 + l15, l16);
      ah[mi] = *(short8*)&As_h[off];
      al[mi] = *(short8*)&As_l[off];
    }
#pragma unroll
    for (int ni = 0; ni < 4; ++ni) {
      int off = ldsoff(wc * 64 + ni * 16 + l15, l16);
      bh[ni] = *(short8*)&Bs_h[off];
      bl[ni] = *(short8*)&Bs_l[off];
    }
#pragma unroll
    for (int mi = 0; mi < 4; ++mi)
#pragma unroll
      for (int ni = 0; ni < 4; ++ni) {
        acc[mi][ni] = __builtin_amdgcn_mfma_f32_16x16x32_bf16(ah[mi], bh[ni], acc[mi][ni], 0, 0, 0);
        acc[mi][ni] = __builtin_amdgcn_mfma_f32_16x16x32_bf16(al[mi], bh[ni], acc[mi][ni], 0, 0, 0);
        acc[mi][ni] = __builtin_amdgcn_mfma_f32_16x16x32_bf16(ah[mi], bl[ni], acc[mi][ni], 0, 0, 0);
      }
    __syncthreads();
  }
#pragma unroll
  for (int mi = 0; mi < 4; ++mi)
#pragma unroll
    for (int ni = 0; ni < 4; ++ni) {
      int rr = row0 + wr * 64 + mi * 16 + l16 * 4;
      int cc = col0 + wc * 64 + ni * 16 + l15;
#pragma unroll
      for (int i = 0; i < 4; ++i)
        Cp[(size_t)(rr + i) * N + cc] = acc[mi][ni][i];
    }
}

// ---------------- single-pass fp16 GEMM, 128x128 tile, BK=64, gload_lds dbuf, XCD swizzle --------
// 1D grid (nblocks % 8 == 0). One barrier per K-tile: sync -> prefetch(t+1) -> MFMA(t).
// MODE 0: f32 out. MODE 1: fp16 out. MODE 2: z epilogue (e0 fp16) -> fp16 out.
// MODE 3: split fp16 out: col<4096 -> C0 (width 4096), col>=4096 -> C1 (width 4096).
template <int MODE>
__global__ __launch_bounds__(256) void k_gemm16(const u16* __restrict__ Ag, const u16* __restrict__ Bg,
                                                void* __restrict__ C0, void* __restrict__ C1,
                                                int M, int N, int K,
                                                const u16* __restrict__ e0, const float* __restrict__ e1,
                                                const float* __restrict__ e2) {
  __shared__ __align__(16) u16 As[2 * 128 * 64];
  __shared__ __align__(16) u16 Bs[2 * 128 * 64];
  const int tid = threadIdx.x;
  const int lane = tid & 63, wave = tid >> 6;
  const int wr = wave >> 1, wc = wave & 1;
  const int l15 = lane & 15, l16 = lane >> 4;
  // bijective XCD swizzle
  const int qx = gridDim.x >> 3;
  const int swz = ((int)blockIdx.x & 7) * qx + ((int)blockIdx.x >> 3);
  const int nbx = N >> 7;
  const int row0 = (swz / nbx) * 128, col0 = (swz % nbx) * 128;
  // staging maps
  u32 gA[4], gB[4], lofs[4];
#pragma unroll
  for (int i = 0; i < 4; ++i) {
    int o = wave * 2048 + i * 512 + lane * 8;
    int row = o >> 6;
    int cg = ((lane & 7) ^ (row & 7)) * 8;
    gA[i] = (u32)(row0 + row) * (u32)K + cg;
    gB[i] = (u32)(col0 + row) * (u32)K + cg;
    lofs[i] = (u32)(wave * 2048 + i * 512);
  }
  f32x4 acc[4][4] = {};
  const int NTILE = K >> 6;
#pragma unroll
  for (int i = 0; i < 4; ++i) {
    GL16(Ag + gA[i], &As[lofs[i]]);
    GL16(Bg + gB[i], &Bs[lofs[i]]);
  }
  for (int t = 0; t < NTILE; ++t) {
    const u32 cb = (u32)(t & 1) * 8192;
    __syncthreads();
    if (t + 1 < NTILE) {
      const u32 nb = cb ^ 8192;
      const int kn = (t + 1) << 6;
#pragma unroll
      for (int i = 0; i < 4; ++i) {
        GL16(Ag + gA[i] + kn, &As[nb + lofs[i]]);
        GL16(Bg + gB[i] + kn, &Bs[nb + lofs[i]]);
      }
    }
#pragma unroll
    for (int kk = 0; kk < 2; ++kk) {
      half8 a[4], b[4];
#pragma unroll
      for (int mi = 0; mi < 4; ++mi) {
        int row = wr * 64 + mi * 16 + l15;
        a[mi] = *(half8*)&As[cb + row * 64 + (((kk * 4 + l16) ^ (l15 & 7)) << 3)];
      }
#pragma unroll
      for (int ni = 0; ni < 4; ++ni) {
        int row = wc * 64 + ni * 16 + l15;
        b[ni] = *(half8*)&Bs[cb + row * 64 + (((kk * 4 + l16) ^ (l15 & 7)) << 3)];
      }
#pragma unroll
      for (int mi = 0; mi < 4; ++mi)
#pragma unroll
        for (int ni = 0; ni < 4; ++ni)
          acc[mi][ni] = __builtin_amdgcn_mfma_f32_16x16x32_f16(a[mi], b[ni], acc[mi][ni], 0, 0, 0);
    }
  }
  // epilogue
  u16* Cs = nullptr;
  int cbase = col0;
  if constexpr (MODE == 3) {
    Cs = (col0 < 4096) ? (u16*)C0 : (u16*)C1;
    cbase = col0 & 4095;
  }
#pragma unroll
  for (int mi = 0; mi < 4; ++mi) {
#pragma unroll
    for (int ni = 0; ni < 4; ++ni) {
      int rr = row0 + wr * 64 + mi * 16 + l16 * 4;
      int cc = col0 + wc * 64 + ni * 16 + l15;
#pragma unroll
      for (int i = 0; i < 4; ++i) {
        float v = acc[mi][ni][i];
        if constexpr (MODE == 0) {
          ((float*)C0)[(size_t)(rr + i) * N + cc] = v;
        } else if constexpr (MODE == 1) {
          ((u16*)C0)[(size_t)(rr + i) * N + cc] = f2h(v);
        } else if constexpr (MODE == 2) {
          size_t idx = (size_t)(rr + i) * N + cc;
          float zs = v * sigm(v);
          float o = h2f(e0[idx]) * e1[(size_t)(rr + i) * 32 + (cc >> 7)] * e2[cc & 127] * zs;
          ((u16*)C0)[idx] = f2h(o);
        } else {
          int c2 = cbase + wc * 64 + ni * 16 + l15;
          Cs[(size_t)(rr + i) * 4096 + c2] = f2h(v);
        }
      }
    }
  }
}

// ---------------- beta / g from 4 split-K partials [4][BT][128], TRANSPOSED out [32][4096] -------
__global__ __launch_bounds__(256) void k_bg(const float* __restrict__ ba, const float* __restrict__ dt_bias,
                                            const float* __restrict__ A_log, float* __restrict__ beta_t,
                                            float* __restrict__ g_t) {
  int i = blockIdx.x * 256 + threadIdx.x;
  int bt = i >> 5, h = i & 31;
  const size_t P = (size_t)4096 * 128;
  float bv = ba[(size_t)bt * 128 + h] + ba[P + (size_t)bt * 128 + h] +
             ba[2 * P + (size_t)bt * 128 + h] + ba[3 * P + (size_t)bt * 128 + h];
  float av = ba[(size_t)bt * 128 + 32 + h] + ba[P + (size_t)bt * 128 + 32 + h] +
             ba[2 * P + (size_t)bt * 128 + 32 + h] + ba[3 * P + (size_t)bt * 128 + 32 + h];
  beta_t[h * 4096 + bt] = sigm(bv);
  float xx = av + dt_bias[h];
  float sp = (xx > 20.f) ? xx : log1pf(__expf(xx));
  g_t[h * 4096 + bt] = -__expf(A_log[h]) * sp;
}

// ---------------- conv+SiLU+L2norm for q,k: fp16 in [4096][4096] -> fp16 out ----------------
__global__ __launch_bounds__(256) void k_convqk(const u16* __restrict__ qkraw, const float* __restrict__ cw,
                                                u16* __restrict__ qkn) {
  __shared__ float sval[4096];
  __shared__ float snrm[32];
  const int tid = threadIdx.x;
  const int bt = blockIdx.x;
  const int b = bt >> 11, t = bt & 2047;
  for (int i = 0; i < 16; ++i) {
    int c = i * 256 + tid;
    float acc = 0.f;
#pragma unroll
    for (int j = 0; j < 4; ++j) {
      int ts = t - 3 + j;
      if (ts >= 0) acc += cw[c * 4 + j] * h2f(qkraw[(size_t)(b * 2048 + ts) * 4096 + c]);
    }
    sval[c] = acc * sigm(acc);
  }
  __syncthreads();
  {
    int gidx = tid >> 3, s = tid & 7;
    float ss = 0.f;
#pragma unroll
    for (int i2 = 0; i2 < 16; ++i2) { float v = sval[gidx * 128 + s * 16 + i2]; ss += v * v; }
    ss += __shfl_xor(ss, 1); ss += __shfl_xor(ss, 2); ss += __shfl_xor(ss, 4);
    if (s == 0) snrm[gidx] = 1.0f / fmaxf(sqrtf(ss), 1e-12f);
  }
  __syncthreads();
  for (int i = 0; i < 16; ++i) {
    int c = i * 256 + tid;
    qkn[(size_t)bt * 4096 + c] = f2h(sval[c] * snrm[c >> 7]);
  }
}

// ---------------- chunked gated-linear-attention scan, single-fp16 MFMA, fp16 out ----------------
__global__ __launch_bounds__(512, 4) void k_scanc(const u16* __restrict__ qk16, const u16* __restrict__ v16,
                                                  const float* __restrict__ cw,
                                                  const float* __restrict__ beta_t, const float* __restrict__ g_t,
                                                  u16* __restrict__ outr) {
  __shared__ __align__(16) u16 Qs[64][136], Ks[64][136];
  __shared__ __align__(16) u16 Vs[32][72];
  __shared__ __align__(16) u16 SIs[64][72];
  __shared__ __align__(16) u16 SH[2][32][132];
  __shared__ u16 rv16[67][36];
  __shared__ float garr[2][64], barr[2][64], warr[2][64], earr[2][64];
  __shared__ float sdt[2];

  const int tid = threadIdx.x;
  const int lane = tid & 63, wv = tid >> 6;
  const int l15 = lane & 15, l16 = lane >> 4;
  const int dq = blockIdx.x & 3, h = (blockIdx.x >> 2) & 31, b = blockIdx.x >> 7;
  const int bT = b * 2048;
  const int hk = h >> 1;
  const int dvl = tid & 31;
  const int vch = h * 128 + dq * 32;
  const float4 cwv = *(const float4*)&cw[(4096 + vch + dvl) * 4];
  const int mblk = wv & 3, nh = wv >> 2;
  const int m0 = mblk * 16;
  const int sr = tid >> 3, d0 = (tid & 7) * 16;
  const int r0v = tid >> 5;

  for (int i = tid; i < 2 * 32 * 132; i += 512) ((u16*)SH)[i] = 0;
  f32x4 st[2] = {};

  short8 pq[2], pk[2];
  u16 pv[5];
  float pgv, pbv;
  auto LOADQK = [&](int t0) {
    const size_t base = (size_t)(bT + t0 + sr) * 4096 + hk * 128 + d0;
    pq[0] = *(const short8*)&qk16[base];        pq[1] = *(const short8*)&qk16[base + 8];
    pk[0] = *(const short8*)&qk16[base + 2048]; pk[1] = *(const short8*)&qk16[base + 2056];
  };
  auto LOADV = [&](int t0) {
#pragma unroll
    for (int i = 0; i < 5; ++i) {
      int r = r0v + i * 16;
      int tr = t0 - 3 + r;
      pv[i] = (r < 67 && tr >= 0) ? v16[(size_t)(bT + tr) * 4096 + vch + dvl] : (u16)0;
    }
  };
  auto CUMSUM = [&](float gv, float bv, int buf) {
    float cum = gv;
#pragma unroll
    for (int off = 1; off < 64; off <<= 1) {
      float o = __shfl_up(cum, off);
      if (lane >= off) cum += o;
    }
    float tot = __shfl(cum, 63);
    garr[buf][lane] = cum;
    earr[buf][lane] = __expf(cum);
    warr[buf][lane] = __expf(tot - cum) * bv;
    barr[buf][lane] = bv;
    if (lane == 0) sdt[buf] = __expf(tot);
  };

  LOADQK(0);
  LOADV(0);
  if (wv == 0) {
    float gv = g_t[h * 4096 + bT + lane];
    float bv = beta_t[h * 4096 + bT + lane];
    CUMSUM(gv, bv, 0);
  }

  for (int ch = 0; ch < NCH; ++ch) {
    const int t0 = ch * CL;
    const int p = ch & 1;
    *(short8*)&Qs[sr][d0] = pq[0]; *(short8*)&Qs[sr][d0 + 8] = pq[1];
    *(short8*)&Ks[sr][d0] = pk[0]; *(short8*)&Ks[sr][d0 + 8] = pk[1];
#pragma unroll
    for (int i = 0; i < 5; ++i) {
      int r = r0v + i * 16;
      if (r < 67) rv16[r][dvl] = pv[i];
    }
    __syncthreads();  // B1
    if (ch + 1 < NCH) {
      LOADQK(t0 + CL);
      LOADV(t0 + CL);
      if (wv == 0) {
        pgv = g_t[h * 4096 + bT + t0 + CL + lane];
        pbv = beta_t[h * 4096 + bT + t0 + CL + lane];
      }
    }
    {
      int tl = tid >> 5;
#pragma unroll
      for (int rr = 0; rr < 4; ++rr) {
        int t = rr * 16 + tl;
        float a = cwv.x * h2f(rv16[t][dvl]) + cwv.y * h2f(rv16[t + 1][dvl]) +
                  cwv.z * h2f(rv16[t + 2][dvl]) + cwv.w * h2f(rv16[t + 3][dvl]);
        a = a * sigm(a);
        Vs[dvl][t] = f2h(a);
      }
    }
    half8 a[4];
#pragma unroll
    for (int kk = 0; kk < 4; ++kk) a[kk] = *(half8*)&Qs[m0 + l15][l16 * 8 + kk * 32];
#pragma unroll
    for (int j = 0; j < 2; ++j) {
      int n = nh * 2 + j;
      f32x4 a4 = {};
#pragma unroll
      for (int kk = 0; kk < 4; ++kk) {
        half8 b8 = *(half8*)&Ks[n * 16 + l15][l16 * 8 + kk * 32];
        a4 = __builtin_amdgcn_mfma_f32_16x16x32_f16(a[kk], b8, a4, 0, 0, 0);
      }
      int col = n * 16 + l15;
      float gc = garr[p][col], bc = barr[p][col];
#pragma unroll
      for (int i = 0; i < 4; ++i) {
        int row = m0 + l16 * 4 + i;
        float cval = (col <= row) ? __expf(garr[p][row] - gc) * bc * a4[i] : 0.f;
        SIs[row][col] = f2h(cval);
      }
    }
    __syncthreads();  // B2
    f32x4 ao = {};
#pragma unroll
    for (int kk = 0; kk < 4; ++kk) {
      half8 s8 = *(half8*)&SH[p][nh * 16 + l15][l16 * 8 + kk * 32];
      ao = __builtin_amdgcn_mfma_f32_16x16x32_f16(a[kk], s8, ao, 0, 0, 0);
    }
#pragma unroll
    for (int i = 0; i < 4; ++i) ao[i] *= earr[p][m0 + l16 * 4 + i];
#pragma unroll
    for (int kk = 0; kk < 2; ++kk) {
      half8 asi = *(half8*)&SIs[m0 + l15][l16 * 8 + kk * 32];
      half8 bv8 = *(half8*)&Vs[nh * 16 + l15][l16 * 8 + kk * 32];
      ao = __builtin_amdgcn_mfma_f32_16x16x32_f16(asi, bv8, ao, 0, 0, 0);
    }
#pragma unroll
    for (int i = 0; i < 4; ++i)
      outr[(size_t)(bT + t0 + m0 + l16 * 4 + i) * 4096 + vch + nh * 16 + l15] = f2h(ao[i]);
    const float sd = sdt[p];
#pragma unroll
    for (int m = 0; m < 2; ++m)
#pragma unroll
      for (int i = 0; i < 4; ++i) st[m][i] *= sd;
#pragma unroll
    for (int kk = 0; kk < 2; ++kk) {
      half8 bw;
      {
        int dk = wv * 16 + l15;
#pragma unroll
        for (int e = 0; e < 8; ++e) {
          int s = l16 * 8 + e + kk * 32;
          bw[e] = (_Float16)(h2f(Ks[s][dk]) * warr[p][s]);
        }
      }
#pragma unroll
      for (int m = 0; m < 2; ++m) {
        half8 av = *(half8*)&Vs[m * 16 + l15][l16 * 8 + kk * 32];
        st[m] = __builtin_amdgcn_mfma_f32_16x16x32_f16(av, bw, st[m], 0, 0, 0);
      }
    }
#pragma unroll
    for (int m = 0; m < 2; ++m)
#pragma unroll
      for (int i = 0; i < 4; ++i)
        SH[p ^ 1][m * 16 + l16 * 4 + i][wv * 16 + l15] = f2h(st[m][i]);
    if (wv == 0 && ch + 1 < NCH) CUMSUM(pgv, pbv, p ^ 1);
    __syncthreads();  // B4
  }
}

// ---------------- per-(bt,head) RMS scale from fp16 outr ----------------
__global__ __launch_bounds__(256) void k_rms(const u16* __restrict__ outr, float* __restrict__ rms) {
  int pair = blockIdx.x * 4 + (threadIdx.x >> 6);
  int lane = threadIdx.x & 63;
  u32 pv = *(const u32*)&outr[(size_t)pair * 128 + lane * 2];
  float v0 = h2f((u16)pv), v1 = h2f((u16)(pv >> 16));
  float ss = v0 * v0 + v1 * v1;
#pragma unroll
  for (int m = 1; m < 64; m <<= 1) ss += __shfl_xor(ss, m);
  if (lane == 0) rms[pair] = rsqrtf(ss * (1.0f / 128.0f) + 1e-6f);
}

extern "C" void kernel_launch(void* const* d_in, const int* in_sizes, int n_in,
                              void* d_out, int out_size, void* d_ws, size_t ws_size,
                              hipStream_t stream) {
  const float* x = (const float*)d_in[0];
  // d_in[1] = positions (int64) — unused by the math
  const float* W_qkv = (const float*)d_in[2];
  const float* W_z = (const float*)d_in[3];
  const float* W_b = (const float*)d_in[4];
  const float* W_a = (const float*)d_in[5];
  const float* conv_w = (const float*)d_in[6];
  const float* dt_bias = (const float*)d_in[7];
  const float* A_log = (const float*)d_in[8];
  const float* norm_w = (const float*)d_in[9];
  const float* W_out = (const float*)d_in[10];
  float* out = (float*)d_out;

  const size_t MB = 1ull << 20;
  const size_t need = 192 * MB + 3 * (size_t)NBT * 32 * 4;  // == proven bound
  if (ws_size < need) {
    k_sentinel<<<1, 1, 0, stream>>>(out);
    return;
  }
  char* ws = (char*)d_ws;
  u16* xh = (u16*)ws;                        // [0,16)
  u16* xl = (u16*)(ws + 16 * MB);            // [16,32)
  u16* xh16 = (u16*)(ws + 32 * MB);          // [32,48)
  u16* wz16 = (u16*)(ws + 48 * MB);          // [48,64)
  u16* qkB16 = (u16*)(ws + 64 * MB);         // [64,96)
  u16* wout16 = (u16*)(ws + 64 * MB);        //   (after scan)
  u16* qkA16 = (u16*)(ws + 96 * MB);         // [96,128)
  u16* om16 = (u16*)(ws + 96 * MB);          //   (after conv... after z) 
  u16* wsh16 = (u16*)(ws + 128 * MB);        // [128,160) W_qkv fp16 full
  u16* outr16 = (u16*)(ws + 128 * MB);       //   (after qkv GEMM)
  u16* v16 = (u16*)(ws + 160 * MB);          // [160,192)
  u16* wbah = (u16*)(ws + 160 * MB);         //   (early, dead before v16)
  u16* wbal = (u16*)(ws + 160 * MB + 512 * 1024);
  float* babuf4 = (float*)(ws + 161 * MB);   //   [161,169) 4 split-K partials (early)
  float* beta_t = (float*)(ws + 192 * MB);
  float* g_t = beta_t + (size_t)NBT * 32;
  float* rmsb = g_t + (size_t)NBT * 32;

  const int N4X = NBT * NC / 4;
  // --- conversions + ba path (split-K x4) ---
  k_cvtx<<<N4X / 256, 256, 0, stream>>>(x, xh, xl, xh16, N4X);
  k_cvt16<<<2 * N4X / 256, 256, 0, stream>>>(W_qkv, wsh16, 2 * N4X);
  k_cvt16<<<N4X / 256, 256, 0, stream>>>(W_z, wz16, N4X);
  k_wba<<<128 * NC / 256, 256, 0, stream>>>(W_b, W_a, wbah, wbal);
  k_gemm_bf3<<<dim3(4, NBT / 128), 256, 0, stream>>>(xh, xl, wbah, wbal, babuf4, NBT, 128, NC);
  k_bg<<<NBT * 32 / 256, 256, 0, stream>>>(babuf4, dt_bias, A_log, beta_t, g_t);

  // --- merged qkv projection (N=8192, split outputs) -> conv ---
  k_gemm16<3><<<(NBT / 128) * (8192 / 128), 256, 0, stream>>>(xh16, wsh16, qkA16, v16,
                                                              NBT, 8192, NC, nullptr, nullptr, nullptr);
  k_convqk<<<NBT, 256, 0, stream>>>(qkA16, conv_w, qkB16);

  // --- chunked scan -> outr16 (overlays wsh16, dead) ---
  k_scanc<<<256, 512, 0, stream>>>(qkB16, v16, conv_w, beta_t, g_t, outr16);
  k_rms<<<NBT * NHV / 4, 256, 0, stream>>>(outr16, rmsb);

  // --- z projection with fused gate epilogue -> om16 (overlays qkA16, dead) ---
  k_gemm16<2><<<(NBT / 128) * (VALD / 128), 256, 0, stream>>>(xh16, wz16, om16, nullptr, NBT, VALD, NC,
                                                              outr16, rmsb, norm_w);

  // --- output projection -> f32 out (wout16 overlays qkB16, dead after scan) ---
  k_cvt16<<<N4X / 256, 256, 0, stream>>>(W_out, wout16, N4X);
  k_gemm16<0><<<(NBT / 128) * (NC / 128), 256, 0, stream>>>(om16, wout16, out, nullptr, NBT, NC, VALD,
                                                            nullptr, nullptr, nullptr);
}

// Round 22
// 571.711 us; speedup vs baseline: 1.4795x; 1.0301x over previous
//
#include <hip/hip_runtime.h>

typedef unsigned short u16;
typedef unsigned int u32;
typedef __attribute__((ext_vector_type(8))) short short8;
typedef __attribute__((ext_vector_type(8))) _Float16 half8;
typedef __attribute__((ext_vector_type(4))) float f32x4;

#define NB 2
#define NT 2048
#define NC 2048
#define NHV 32
#define VALD 4096
#define NBT 4096
#define CL 64
#define NCH (NT / CL)

#define GL16(gp, lp) __builtin_amdgcn_global_load_lds( \
    (const __attribute__((address_space(1))) unsigned int*)(gp), \
    (__attribute__((address_space(3))) unsigned int*)(lp), 16, 0, 0)

static __device__ __forceinline__ float bf2f(u16 u) {
  union { u32 u; float f; } x; x.u = ((u32)u) << 16; return x.f;
}
static __device__ __forceinline__ u16 f2bf(float f) {
  union { float f; u32 u; } x; x.f = f;
  u32 r = x.u + 0x7fffu + ((x.u >> 16) & 1u);
  return (u16)(r >> 16);
}
static __device__ __forceinline__ u16 f2h(float f) {
  union { _Float16 h; u16 u; } c; c.h = (_Float16)f; return c.u;
}
static __device__ __forceinline__ float h2f(u16 u) {
  union { u16 u; _Float16 h; } c; c.u = u; return (float)c.h;
}
static __device__ __forceinline__ float sigm(float x) { return 1.0f / (1.0f + __expf(-x)); }
static __device__ __forceinline__ int ldsoff(int row, int c8) {
  return row * 48 + ((c8 ^ ((row >> 2) & 3)) << 3);
}

// ---------------- sentinel ----------------
__global__ void k_sentinel(float* out) { out[0] = 1.0e6f; }

// ---------------- x -> bf16 hi/lo planes + fp16 plane (single read of x) ----------------
__global__ __launch_bounds__(256) void k_cvtx(const float* __restrict__ in, u16* __restrict__ hi,
                                              u16* __restrict__ lo, u16* __restrict__ h16, int n4) {
  int i = blockIdx.x * 256 + threadIdx.x;
  if (i >= n4) return;
  float4 v = ((const float4*)in)[i];
  ushort4 h, l, p;
  h.x = f2bf(v.x); l.x = f2bf(v.x - bf2f(h.x)); p.x = f2h(v.x);
  h.y = f2bf(v.y); l.y = f2bf(v.y - bf2f(h.y)); p.y = f2h(v.y);
  h.z = f2bf(v.z); l.z = f2bf(v.z - bf2f(h.z)); p.z = f2h(v.z);
  h.w = f2bf(v.w); l.w = f2bf(v.w - bf2f(h.w)); p.w = f2h(v.w);
  ((ushort4*)hi)[i] = h;
  ((ushort4*)lo)[i] = l;
  ((ushort4*)h16)[i] = p;
}

// ---------------- f32 -> fp16 plane ----------------
__global__ __launch_bounds__(256) void k_cvt16(const float* __restrict__ in, u16* __restrict__ out, int n4) {
  int i = blockIdx.x * 256 + threadIdx.x;
  if (i >= n4) return;
  float4 v = ((const float4*)in)[i];
  ushort4 o;
  o.x = f2h(v.x); o.y = f2h(v.y); o.z = f2h(v.z); o.w = f2h(v.w);
  ((ushort4*)out)[i] = o;
}

// ---------------- build padded W_ba hi/lo bf16 planes [128][2048] ----------------
__global__ __launch_bounds__(256) void k_wba(const float* __restrict__ Wb, const float* __restrict__ Wa,
                                             u16* __restrict__ hi, u16* __restrict__ lo) {
  int i = blockIdx.x * 256 + threadIdx.x;
  int r = i >> 11, c = i & 2047;
  float v = 0.f;
  if (r < 32) v = Wb[r * 2048 + c];
  else if (r < 64) v = Wa[(r - 32) * 2048 + c];
  u16 h = f2bf(v);
  hi[i] = h;
  lo[i] = f2bf(v - bf2f(h));
}

// ---------------- 3-pass bf16 GEMM, split-K x4 (ba projection) ----------------
__global__ __launch_bounds__(256) void k_gemm_bf3(const u16* __restrict__ Ahg, const u16* __restrict__ Alg,
                                                  const u16* __restrict__ Bhg, const u16* __restrict__ Blg,
                                                  float* __restrict__ C0, int M, int N, int K) {
  __shared__ __align__(16) u16 As_h[128 * 48];
  __shared__ __align__(16) u16 As_l[128 * 48];
  __shared__ __align__(16) u16 Bs_h[128 * 48];
  __shared__ __align__(16) u16 Bs_l[128 * 48];
  const int tid = threadIdx.x;
  const int lane = tid & 63, wave = tid >> 6;
  const int wr = wave >> 1, wc = wave & 1;
  const int l15 = lane & 15, l16 = lane >> 4;
  const int kc = blockIdx.x;
  const int Kc = K >> 2;
  const int kbase = kc * Kc;
  const int row0 = blockIdx.y * 128, col0 = 0;
  float* Cp = C0 + (size_t)kc * M * N;
  const int sr = tid >> 1, sk = (tid & 1) * 16;
  const int c0 = sk >> 3;
  const int w0 = ldsoff(sr, c0), w1 = ldsoff(sr, c0 + 1);
  f32x4 acc[4][4] = {};
  for (int k0 = kbase; k0 < kbase + Kc; k0 += 32) {
    const size_t aoff = (size_t)(row0 + sr) * K + k0 + sk;
    const size_t boff = (size_t)(col0 + sr) * K + k0 + sk;
    *(short8*)&As_h[w0] = *(const short8*)&Ahg[aoff];
    *(short8*)&As_h[w1] = *(const short8*)&Ahg[aoff + 8];
    *(short8*)&As_l[w0] = *(const short8*)&Alg[aoff];
    *(short8*)&As_l[w1] = *(const short8*)&Alg[aoff + 8];
    *(short8*)&Bs_h[w0] = *(const short8*)&Bhg[boff];
    *(short8*)&Bs_h[w1] = *(const short8*)&Bhg[boff + 8];
    *(short8*)&Bs_l[w0] = *(const short8*)&Blg[boff];
    *(short8*)&Bs_l[w1] = *(const short8*)&Blg[boff + 8];
    __syncthreads();
    short8 ah[4], al[4], bh[4], bl[4];
#pragma unroll
    for (int mi = 0; mi < 4; ++mi) {
      int off = ldsoff(wr * 64 + mi * 16 + l15, l16);
      ah[mi] = *(short8*)&As_h[off];
      al[mi] = *(short8*)&As_l[off];
    }
#pragma unroll
    for (int ni = 0; ni < 4; ++ni) {
      int off = ldsoff(wc * 64 + ni * 16 + l15, l16);
      bh[ni] = *(short8*)&Bs_h[off];
      bl[ni] = *(short8*)&Bs_l[off];
    }
#pragma unroll
    for (int mi = 0; mi < 4; ++mi)
#pragma unroll
      for (int ni = 0; ni < 4; ++ni) {
        acc[mi][ni] = __builtin_amdgcn_mfma_f32_16x16x32_bf16(ah[mi], bh[ni], acc[mi][ni], 0, 0, 0);
        acc[mi][ni] = __builtin_amdgcn_mfma_f32_16x16x32_bf16(al[mi], bh[ni], acc[mi][ni], 0, 0, 0);
        acc[mi][ni] = __builtin_amdgcn_mfma_f32_16x16x32_bf16(ah[mi], bl[ni], acc[mi][ni], 0, 0, 0);
      }
    __syncthreads();
  }
#pragma unroll
  for (int mi = 0; mi < 4; ++mi)
#pragma unroll
    for (int ni = 0; ni < 4; ++ni) {
      int rr = row0 + wr * 64 + mi * 16 + l16 * 4;
      int cc = col0 + wc * 64 + ni * 16 + l15;
#pragma unroll
      for (int i = 0; i < 4; ++i)
        Cp[(size_t)(rr + i) * N + cc] = acc[mi][ni][i];
    }
}

// ---------------- single-pass fp16 GEMM, 128x128 tile, BK=64, gload_lds dbuf ----------------
// 2D-supertile XCD ordering: each XCD's contiguous chunk covers an SRxSC tile region
// (SC=min(16,nbx), SR=chunk/SC) -> per-XCD L2 working set = SR A-panels + SC B-panels.
// One barrier per K-tile: sync -> prefetch(t+1) -> MFMA(t).
// MODE 0: f32 out. MODE 1: fp16 out. MODE 2: z epilogue (e0 fp16) -> fp16 out.
// MODE 3: split fp16 out: col<4096 -> C0, col>=4096 -> C1 (both width 4096).
template <int MODE>
__global__ __launch_bounds__(256) void k_gemm16(const u16* __restrict__ Ag, const u16* __restrict__ Bg,
                                                void* __restrict__ C0, void* __restrict__ C1,
                                                int M, int N, int K,
                                                const u16* __restrict__ e0, const float* __restrict__ e1,
                                                const float* __restrict__ e2) {
  __shared__ __align__(16) u16 As[2 * 128 * 64];
  __shared__ __align__(16) u16 Bs[2 * 128 * 64];
  const int tid = threadIdx.x;
  const int lane = tid & 63, wave = tid >> 6;
  const int wr = wave >> 1, wc = wave & 1;
  const int l15 = lane & 15, l16 = lane >> 4;
  // 2D-supertile XCD mapping (bid&7 = XCD; t = position within XCD chunk)
  const int nbx = N >> 7;
  const int chunk = (int)gridDim.x >> 3;
  const int reg = (int)blockIdx.x & 7;
  const int t0i = (int)blockIdx.x >> 3;
  const int SC = (nbx < 16) ? nbx : 16;
  const int SR = chunk / SC;
  const int regc = nbx / SC;  // regions per row-band
  const int row0 = ((reg / regc) * SR + t0i / SC) * 128;
  const int col0 = ((reg % regc) * SC + t0i % SC) * 128;
  // staging maps
  u32 gA[4], gB[4], lofs[4];
#pragma unroll
  for (int i = 0; i < 4; ++i) {
    int o = wave * 2048 + i * 512 + lane * 8;
    int row = o >> 6;
    int cg = ((lane & 7) ^ (row & 7)) * 8;
    gA[i] = (u32)(row0 + row) * (u32)K + cg;
    gB[i] = (u32)(col0 + row) * (u32)K + cg;
    lofs[i] = (u32)(wave * 2048 + i * 512);
  }
  f32x4 acc[4][4] = {};
  const int NTILE = K >> 6;
#pragma unroll
  for (int i = 0; i < 4; ++i) {
    GL16(Ag + gA[i], &As[lofs[i]]);
    GL16(Bg + gB[i], &Bs[lofs[i]]);
  }
  for (int t = 0; t < NTILE; ++t) {
    const u32 cb = (u32)(t & 1) * 8192;
    __syncthreads();
    if (t + 1 < NTILE) {
      const u32 nb = cb ^ 8192;
      const int kn = (t + 1) << 6;
#pragma unroll
      for (int i = 0; i < 4; ++i) {
        GL16(Ag + gA[i] + kn, &As[nb + lofs[i]]);
        GL16(Bg + gB[i] + kn, &Bs[nb + lofs[i]]);
      }
    }
#pragma unroll
    for (int kk = 0; kk < 2; ++kk) {
      half8 a[4], b[4];
#pragma unroll
      for (int mi = 0; mi < 4; ++mi) {
        int row = wr * 64 + mi * 16 + l15;
        a[mi] = *(half8*)&As[cb + row * 64 + (((kk * 4 + l16) ^ (l15 & 7)) << 3)];
      }
#pragma unroll
      for (int ni = 0; ni < 4; ++ni) {
        int row = wc * 64 + ni * 16 + l15;
        b[ni] = *(half8*)&Bs[cb + row * 64 + (((kk * 4 + l16) ^ (l15 & 7)) << 3)];
      }
#pragma unroll
      for (int mi = 0; mi < 4; ++mi)
#pragma unroll
        for (int ni = 0; ni < 4; ++ni)
          acc[mi][ni] = __builtin_amdgcn_mfma_f32_16x16x32_f16(a[mi], b[ni], acc[mi][ni], 0, 0, 0);
    }
  }
  // epilogue
  u16* Cs = nullptr;
  int cbase = col0;
  if constexpr (MODE == 3) {
    Cs = (col0 < 4096) ? (u16*)C0 : (u16*)C1;
    cbase = col0 & 4095;
  }
#pragma unroll
  for (int mi = 0; mi < 4; ++mi) {
#pragma unroll
    for (int ni = 0; ni < 4; ++ni) {
      int rr = row0 + wr * 64 + mi * 16 + l16 * 4;
      int cc = col0 + wc * 64 + ni * 16 + l15;
#pragma unroll
      for (int i = 0; i < 4; ++i) {
        float v = acc[mi][ni][i];
        if constexpr (MODE == 0) {
          ((float*)C0)[(size_t)(rr + i) * N + cc] = v;
        } else if constexpr (MODE == 1) {
          ((u16*)C0)[(size_t)(rr + i) * N + cc] = f2h(v);
        } else if constexpr (MODE == 2) {
          size_t idx = (size_t)(rr + i) * N + cc;
          float zs = v * sigm(v);
          float o = h2f(e0[idx]) * e1[(size_t)(rr + i) * 32 + (cc >> 7)] * e2[cc & 127] * zs;
          ((u16*)C0)[idx] = f2h(o);
        } else {
          int c2 = cbase + wc * 64 + ni * 16 + l15;
          Cs[(size_t)(rr + i) * 4096 + c2] = f2h(v);
        }
      }
    }
  }
}

// ---------------- beta / g from 4 split-K partials [4][BT][128], TRANSPOSED out [32][4096] -------
__global__ __launch_bounds__(256) void k_bg(const float* __restrict__ ba, const float* __restrict__ dt_bias,
                                            const float* __restrict__ A_log, float* __restrict__ beta_t,
                                            float* __restrict__ g_t) {
  int i = blockIdx.x * 256 + threadIdx.x;
  int bt = i >> 5, h = i & 31;
  const size_t P = (size_t)4096 * 128;
  float bv = ba[(size_t)bt * 128 + h] + ba[P + (size_t)bt * 128 + h] +
             ba[2 * P + (size_t)bt * 128 + h] + ba[3 * P + (size_t)bt * 128 + h];
  float av = ba[(size_t)bt * 128 + 32 + h] + ba[P + (size_t)bt * 128 + 32 + h] +
             ba[2 * P + (size_t)bt * 128 + 32 + h] + ba[3 * P + (size_t)bt * 128 + 32 + h];
  beta_t[h * 4096 + bt] = sigm(bv);
  float xx = av + dt_bias[h];
  float sp = (xx > 20.f) ? xx : log1pf(__expf(xx));
  g_t[h * 4096 + bt] = -__expf(A_log[h]) * sp;
}

// ---------------- conv+SiLU+L2norm for q,k: fp16 in [4096][4096] -> fp16 out ----------------
__global__ __launch_bounds__(256) void k_convqk(const u16* __restrict__ qkraw, const float* __restrict__ cw,
                                                u16* __restrict__ qkn) {
  __shared__ float sval[4096];
  __shared__ float snrm[32];
  const int tid = threadIdx.x;
  const int bt = blockIdx.x;
  const int b = bt >> 11, t = bt & 2047;
  for (int i = 0; i < 16; ++i) {
    int c = i * 256 + tid;
    float acc = 0.f;
#pragma unroll
    for (int j = 0; j < 4; ++j) {
      int ts = t - 3 + j;
      if (ts >= 0) acc += cw[c * 4 + j] * h2f(qkraw[(size_t)(b * 2048 + ts) * 4096 + c]);
    }
    sval[c] = acc * sigm(acc);
  }
  __syncthreads();
  {
    int gidx = tid >> 3, s = tid & 7;
    float ss = 0.f;
#pragma unroll
    for (int i2 = 0; i2 < 16; ++i2) { float v = sval[gidx * 128 + s * 16 + i2]; ss += v * v; }
    ss += __shfl_xor(ss, 1); ss += __shfl_xor(ss, 2); ss += __shfl_xor(ss, 4);
    if (s == 0) snrm[gidx] = 1.0f / fmaxf(sqrtf(ss), 1e-12f);
  }
  __syncthreads();
  for (int i = 0; i < 16; ++i) {
    int c = i * 256 + tid;
    qkn[(size_t)bt * 4096 + c] = f2h(sval[c] * snrm[c >> 7]);
  }
}

// ---------------- chunked gated-linear-attention scan, single-fp16 MFMA, fp16 out ----------------
__global__ __launch_bounds__(512, 4) void k_scanc(const u16* __restrict__ qk16, const u16* __restrict__ v16,
                                                  const float* __restrict__ cw,
                                                  const float* __restrict__ beta_t, const float* __restrict__ g_t,
                                                  u16* __restrict__ outr) {
  __shared__ __align__(16) u16 Qs[64][136], Ks[64][136];
  __shared__ __align__(16) u16 Vs[32][72];
  __shared__ __align__(16) u16 SIs[64][72];
  __shared__ __align__(16) u16 SH[2][32][132];
  __shared__ u16 rv16[67][36];
  __shared__ float garr[2][64], barr[2][64], warr[2][64], earr[2][64];
  __shared__ float sdt[2];

  const int tid = threadIdx.x;
  const int lane = tid & 63, wv = tid >> 6;
  const int l15 = lane & 15, l16 = lane >> 4;
  const int dq = blockIdx.x & 3, h = (blockIdx.x >> 2) & 31, b = blockIdx.x >> 7;
  const int bT = b * 2048;
  const int hk = h >> 1;
  const int dvl = tid & 31;
  const int vch = h * 128 + dq * 32;
  const float4 cwv = *(const float4*)&cw[(4096 + vch + dvl) * 4];
  const int mblk = wv & 3, nh = wv >> 2;
  const int m0 = mblk * 16;
  const int sr = tid >> 3, d0 = (tid & 7) * 16;
  const int r0v = tid >> 5;

  for (int i = tid; i < 2 * 32 * 132; i += 512) ((u16*)SH)[i] = 0;
  f32x4 st[2] = {};

  short8 pq[2], pk[2];
  u16 pv[5];
  float pgv, pbv;
  auto LOADQK = [&](int t0) {
    const size_t base = (size_t)(bT + t0 + sr) * 4096 + hk * 128 + d0;
    pq[0] = *(const short8*)&qk16[base];        pq[1] = *(const short8*)&qk16[base + 8];
    pk[0] = *(const short8*)&qk16[base + 2048]; pk[1] = *(const short8*)&qk16[base + 2056];
  };
  auto LOADV = [&](int t0) {
#pragma unroll
    for (int i = 0; i < 5; ++i) {
      int r = r0v + i * 16;
      int tr = t0 - 3 + r;
      pv[i] = (r < 67 && tr >= 0) ? v16[(size_t)(bT + tr) * 4096 + vch + dvl] : (u16)0;
    }
  };
  auto CUMSUM = [&](float gv, float bv, int buf) {
    float cum = gv;
#pragma unroll
    for (int off = 1; off < 64; off <<= 1) {
      float o = __shfl_up(cum, off);
      if (lane >= off) cum += o;
    }
    float tot = __shfl(cum, 63);
    garr[buf][lane] = cum;
    earr[buf][lane] = __expf(cum);
    warr[buf][lane] = __expf(tot - cum) * bv;
    barr[buf][lane] = bv;
    if (lane == 0) sdt[buf] = __expf(tot);
  };

  LOADQK(0);
  LOADV(0);
  if (wv == 0) {
    float gv = g_t[h * 4096 + bT + lane];
    float bv = beta_t[h * 4096 + bT + lane];
    CUMSUM(gv, bv, 0);
  }

  for (int ch = 0; ch < NCH; ++ch) {
    const int t0 = ch * CL;
    const int p = ch & 1;
    *(short8*)&Qs[sr][d0] = pq[0]; *(short8*)&Qs[sr][d0 + 8] = pq[1];
    *(short8*)&Ks[sr][d0] = pk[0]; *(short8*)&Ks[sr][d0 + 8] = pk[1];
#pragma unroll
    for (int i = 0; i < 5; ++i) {
      int r = r0v + i * 16;
      if (r < 67) rv16[r][dvl] = pv[i];
    }
    __syncthreads();  // B1
    if (ch + 1 < NCH) {
      LOADQK(t0 + CL);
      LOADV(t0 + CL);
      if (wv == 0) {
        pgv = g_t[h * 4096 + bT + t0 + CL + lane];
        pbv = beta_t[h * 4096 + bT + t0 + CL + lane];
      }
    }
    {
      int tl = tid >> 5;
#pragma unroll
      for (int rr = 0; rr < 4; ++rr) {
        int t = rr * 16 + tl;
        float a = cwv.x * h2f(rv16[t][dvl]) + cwv.y * h2f(rv16[t + 1][dvl]) +
                  cwv.z * h2f(rv16[t + 2][dvl]) + cwv.w * h2f(rv16[t + 3][dvl]);
        a = a * sigm(a);
        Vs[dvl][t] = f2h(a);
      }
    }
    half8 a[4];
#pragma unroll
    for (int kk = 0; kk < 4; ++kk) a[kk] = *(half8*)&Qs[m0 + l15][l16 * 8 + kk * 32];
#pragma unroll
    for (int j = 0; j < 2; ++j) {
      int n = nh * 2 + j;
      f32x4 a4 = {};
#pragma unroll
      for (int kk = 0; kk < 4; ++kk) {
        half8 b8 = *(half8*)&Ks[n * 16 + l15][l16 * 8 + kk * 32];
        a4 = __builtin_amdgcn_mfma_f32_16x16x32_f16(a[kk], b8, a4, 0, 0, 0);
      }
      int col = n * 16 + l15;
      float gc = garr[p][col], bc = barr[p][col];
#pragma unroll
      for (int i = 0; i < 4; ++i) {
        int row = m0 + l16 * 4 + i;
        float cval = (col <= row) ? __expf(garr[p][row] - gc) * bc * a4[i] : 0.f;
        SIs[row][col] = f2h(cval);
      }
    }
    __syncthreads();  // B2
    f32x4 ao = {};
#pragma unroll
    for (int kk = 0; kk < 4; ++kk) {
      half8 s8 = *(half8*)&SH[p][nh * 16 + l15][l16 * 8 + kk * 32];
      ao = __builtin_amdgcn_mfma_f32_16x16x32_f16(a[kk], s8, ao, 0, 0, 0);
    }
#pragma unroll
    for (int i = 0; i < 4; ++i) ao[i] *= earr[p][m0 + l16 * 4 + i];
#pragma unroll
    for (int kk = 0; kk < 2; ++kk) {
      half8 asi = *(half8*)&SIs[m0 + l15][l16 * 8 + kk * 32];
      half8 bv8 = *(half8*)&Vs[nh * 16 + l15][l16 * 8 + kk * 32];
      ao = __builtin_amdgcn_mfma_f32_16x16x32_f16(asi, bv8, ao, 0, 0, 0);
    }
#pragma unroll
    for (int i = 0; i < 4; ++i)
      outr[(size_t)(bT + t0 + m0 + l16 * 4 + i) * 4096 + vch + nh * 16 + l15] = f2h(ao[i]);
    const float sd = sdt[p];
#pragma unroll
    for (int m = 0; m < 2; ++m)
#pragma unroll
      for (int i = 0; i < 4; ++i) st[m][i] *= sd;
#pragma unroll
    for (int kk = 0; kk < 2; ++kk) {
      half8 bw;
      {
        int dk = wv * 16 + l15;
#pragma unroll
        for (int e = 0; e < 8; ++e) {
          int s = l16 * 8 + e + kk * 32;
          bw[e] = (_Float16)(h2f(Ks[s][dk]) * warr[p][s]);
        }
      }
#pragma unroll
      for (int m = 0; m < 2; ++m) {
        half8 av = *(half8*)&Vs[m * 16 + l15][l16 * 8 + kk * 32];
        st[m] = __builtin_amdgcn_mfma_f32_16x16x32_f16(av, bw, st[m], 0, 0, 0);
      }
    }
#pragma unroll
    for (int m = 0; m < 2; ++m)
#pragma unroll
      for (int i = 0; i < 4; ++i)
        SH[p ^ 1][m * 16 + l16 * 4 + i][wv * 16 + l15] = f2h(st[m][i]);
    if (wv == 0 && ch + 1 < NCH) CUMSUM(pgv, pbv, p ^ 1);
    __syncthreads();  // B4
  }
}

// ---------------- per-(bt,head) RMS scale from fp16 outr ----------------
__global__ __launch_bounds__(256) void k_rms(const u16* __restrict__ outr, float* __restrict__ rms) {
  int pair = blockIdx.x * 4 + (threadIdx.x >> 6);
  int lane = threadIdx.x & 63;
  u32 pv = *(const u32*)&outr[(size_t)pair * 128 + lane * 2];
  float v0 = h2f((u16)pv), v1 = h2f((u16)(pv >> 16));
  float ss = v0 * v0 + v1 * v1;
#pragma unroll
  for (int m = 1; m < 64; m <<= 1) ss += __shfl_xor(ss, m);
  if (lane == 0) rms[pair] = rsqrtf(ss * (1.0f / 128.0f) + 1e-6f);
}

extern "C" void kernel_launch(void* const* d_in, const int* in_sizes, int n_in,
                              void* d_out, int out_size, void* d_ws, size_t ws_size,
                              hipStream_t stream) {
  const float* x = (const float*)d_in[0];
  // d_in[1] = positions (int64) — unused by the math
  const float* W_qkv = (const float*)d_in[2];
  const float* W_z = (const float*)d_in[3];
  const float* W_b = (const float*)d_in[4];
  const float* W_a = (const float*)d_in[5];
  const float* conv_w = (const float*)d_in[6];
  const float* dt_bias = (const float*)d_in[7];
  const float* A_log = (const float*)d_in[8];
  const float* norm_w = (const float*)d_in[9];
  const float* W_out = (const float*)d_in[10];
  float* out = (float*)d_out;

  const size_t MB = 1ull << 20;
  const size_t need = 192 * MB + 3 * (size_t)NBT * 32 * 4;  // == proven bound
  if (ws_size < need) {
    k_sentinel<<<1, 1, 0, stream>>>(out);
    return;
  }
  char* ws = (char*)d_ws;
  u16* xh = (u16*)ws;                        // [0,16)
  u16* xl = (u16*)(ws + 16 * MB);            // [16,32)
  u16* xh16 = (u16*)(ws + 32 * MB);          // [32,48)
  u16* wz16 = (u16*)(ws + 48 * MB);          // [48,64)
  u16* qkB16 = (u16*)(ws + 64 * MB);         // [64,96)
  u16* wout16 = (u16*)(ws + 64 * MB);        //   (after scan)
  u16* qkA16 = (u16*)(ws + 96 * MB);         // [96,128)
  u16* om16 = (u16*)(ws + 96 * MB);          //   (after conv / z)
  u16* wsh16 = (u16*)(ws + 128 * MB);        // [128,160) W_qkv fp16 full
  u16* outr16 = (u16*)(ws + 128 * MB);       //   (after qkv GEMM)
  u16* v16 = (u16*)(ws + 160 * MB);          // [160,192)
  u16* wbah = (u16*)(ws + 160 * MB);         //   (early, dead before v16)
  u16* wbal = (u16*)(ws + 160 * MB + 512 * 1024);
  float* babuf4 = (float*)(ws + 161 * MB);   //   [161,169) 4 split-K partials (early)
  float* beta_t = (float*)(ws + 192 * MB);
  float* g_t = beta_t + (size_t)NBT * 32;
  float* rmsb = g_t + (size_t)NBT * 32;

  const int N4X = NBT * NC / 4;
  // --- conversions + ba path (split-K x4) ---
  k_cvtx<<<N4X / 256, 256, 0, stream>>>(x, xh, xl, xh16, N4X);
  k_cvt16<<<2 * N4X / 256, 256, 0, stream>>>(W_qkv, wsh16, 2 * N4X);
  k_cvt16<<<N4X / 256, 256, 0, stream>>>(W_z, wz16, N4X);
  k_wba<<<128 * NC / 256, 256, 0, stream>>>(W_b, W_a, wbah, wbal);
  k_gemm_bf3<<<dim3(4, NBT / 128), 256, 0, stream>>>(xh, xl, wbah, wbal, babuf4, NBT, 128, NC);
  k_bg<<<NBT * 32 / 256, 256, 0, stream>>>(babuf4, dt_bias, A_log, beta_t, g_t);

  // --- merged qkv projection (N=8192, split outputs) -> conv ---
  k_gemm16<3><<<(NBT / 128) * (8192 / 128), 256, 0, stream>>>(xh16, wsh16, qkA16, v16,
                                                              NBT, 8192, NC, nullptr, nullptr, nullptr);
  k_convqk<<<NBT, 256, 0, stream>>>(qkA16, conv_w, qkB16);

  // --- chunked scan -> outr16 (overlays wsh16, dead) ---
  k_scanc<<<256, 512, 0, stream>>>(qkB16, v16, conv_w, beta_t, g_t, outr16);
  k_rms<<<NBT * NHV / 4, 256, 0, stream>>>(outr16, rmsb);

  // --- z projection with fused gate epilogue -> om16 (overlays qkA16, dead) ---
  k_gemm16<2><<<(NBT / 128) * (VALD / 128), 256, 0, stream>>>(xh16, wz16, om16, nullptr, NBT, VALD, NC,
                                                              outr16, rmsb, norm_w);

  // --- output projection -> f32 out (wout16 overlays qkB16, dead after scan) ---
  k_cvt16<<<N4X / 256, 256, 0, stream>>>(W_out, wout16, N4X);
  k_gemm16<0><<<(NBT / 128) * (NC / 128), 256, 0, stream>>>(om16, wout16, out, nullptr, NBT, NC, VALD,
                                                            nullptr, nullptr, nullptr);
}